// Round 1
// baseline (726.507 us; speedup 1.0000x reference)
//
#include <hip/hip_runtime.h>
#include <hip/hip_bf16.h>
#include <math.h>

constexpr int Bc = 2, Lc = 2048, Dc = 1024, Hc = 16, HDc = 64, FFc = 4096;
constexpr int NT = Bc * Lc;              // 4096 tokens
constexpr size_t TD = (size_t)NT * Dc;   // 4194304 elements per [B,L,D] tensor
constexpr size_t MEG = 1024 * 1024;

__device__ __forceinline__ float ldf(const float* p) { return *p; }
__device__ __forceinline__ unsigned short f2b(float f) {
  __hip_bfloat16 h = __float2bfloat16(f);
  return *reinterpret_cast<unsigned short*>(&h);
}

using frag   = __attribute__((ext_vector_type(8))) short;   // 8 bf16 (4 VGPRs)
using f32x4v = __attribute__((ext_vector_type(4))) float;   // MFMA C/D

// async global -> LDS, 16B per lane; LDS dest = wave-uniform base + lane*16
__device__ __forceinline__ void async16(const unsigned short* g, unsigned short* l) {
  __builtin_amdgcn_global_load_lds(
      (const __attribute__((address_space(1))) unsigned int*)g,
      (__attribute__((address_space(3))) unsigned int*)l, 16, 0, 0);
}

// ---------- block reductions (blockDim.x == 256 = 4 waves) ----------
__device__ __forceinline__ float block_sum(float v, float* red) {
  const int lane = threadIdx.x & 63, w = threadIdx.x >> 6;
  #pragma unroll
  for (int o = 32; o > 0; o >>= 1) v += __shfl_down(v, o, 64);
  __syncthreads();
  if (lane == 0) red[w] = v;
  __syncthreads();
  return red[0] + red[1] + red[2] + red[3];
}

// ---------- fp32 -> bf16 convert ----------
__global__ __launch_bounds__(256)
void convert_bf16_kernel(const float* __restrict__ IN, unsigned short* __restrict__ OUT)
{
  const size_t gid = (size_t)blockIdx.x * 256 + threadIdx.x;
  const float4 v = *(const float4*)(IN + gid * 4);
  ushort4 o;
  o.x = f2b(v.x); o.y = f2b(v.y); o.z = f2b(v.z); o.w = f2b(v.w);
  *(ushort4*)(OUT + gid * 4) = o;
}

// ---------- fp32 [R,C] -> bf16 [C,R] transpose-convert (z-batched) ----------
__global__ __launch_bounds__(256)
void transpose_convert_kernel(const float* __restrict__ IN, unsigned short* __restrict__ OUT,
                              int R, int C, long long sIn, long long sOut)
{
  __shared__ float tile[64][65];
  const int t = threadIdx.x;
  const float* in = IN + (long long)blockIdx.z * sIn;
  unsigned short* out = OUT + (long long)blockIdx.z * sOut;
  const int r0 = blockIdx.y * 64, c0 = blockIdx.x * 64;
  #pragma unroll
  for (int i = 0; i < 4; i++) {
    const int r = (t >> 4) + i * 16, c4 = (t & 15) * 4;
    const float4 v = *(const float4*)(in + (size_t)(r0 + r) * C + c0 + c4);
    tile[r][c4+0] = v.x; tile[r][c4+1] = v.y; tile[r][c4+2] = v.z; tile[r][c4+3] = v.w;
  }
  __syncthreads();
  #pragma unroll
  for (int i = 0; i < 4; i++) {
    const int cc = (t >> 4) + i * 16, rr4 = (t & 15) * 4;
    ushort4 o;
    o.x = f2b(tile[rr4+0][cc]); o.y = f2b(tile[rr4+1][cc]);
    o.z = f2b(tile[rr4+2][cc]); o.w = f2b(tile[rr4+3][cc]);
    *(ushort4*)(out + (size_t)(c0 + cc) * R + r0 + rr4) = o;
  }
}

// ---------- fused weight transposes: 10 segments in one launch ----------
struct TPack {
  const float* in[10]; unsigned short* out[10];
  int R[10], C[10], tx[10], start[10];
};
__global__ __launch_bounds__(256)
void fused_transpose_kernel(TPack p)
{
  __shared__ float tile[64][65];
  const int bid = blockIdx.x;
  int s = 0;
  #pragma unroll
  for (int i = 1; i < 10; i++) s = (bid >= p.start[i]) ? i : s;
  const float* in = p.in[s];
  unsigned short* out = p.out[s];
  const int R = p.R[s], C = p.C[s];
  const int local = bid - p.start[s];
  const int bx = local % p.tx[s], by = local / p.tx[s];
  const int r0 = by * 64, c0 = bx * 64;
  const int t = threadIdx.x;
  #pragma unroll
  for (int i = 0; i < 4; i++) {
    const int r = (t >> 4) + i * 16, c4 = (t & 15) * 4;
    const float4 v = *(const float4*)(in + (size_t)(r0 + r) * C + c0 + c4);
    tile[r][c4+0] = v.x; tile[r][c4+1] = v.y; tile[r][c4+2] = v.z; tile[r][c4+3] = v.w;
  }
  __syncthreads();
  #pragma unroll
  for (int i = 0; i < 4; i++) {
    const int cc = (t >> 4) + i * 16, rr4 = (t & 15) * 4;
    ushort4 o;
    o.x = f2b(tile[rr4+0][cc]); o.y = f2b(tile[rr4+1][cc]);
    o.z = f2b(tile[rr4+2][cc]); o.w = f2b(tile[rr4+3][cc]);
    *(ushort4*)(out + (size_t)(c0 + cc) * R + r0 + rr4) = o;
  }
}

// ---------- MFMA bf16 GEMM, global_load_lds staging ----------
// C[m,n] = sum_k A[m,k] * Bt[n,k]. Tile BM x 128, BK=32.
// BM=128: 4 waves as 2x2 of 64x64, acc[4][4].
// BM=64 : 4 waves as 1x4 of 64x32, acc[4][2] (more blocks for grid-starved shapes).
// LDS [row][granule^(row&3)][8]; bank swizzle applied via the GLOBAL source index.
constexpr int EPI_BIAS = 0, EPI_BIAS_ROW = 1, EPI_GELU = 2, EPI_ADD = 3, EPI_ADDROW0 = 4,
              EPI_QKV = 5;

template<int BM, int EPI, bool OUTBF, bool OUTBOTH>
__global__ __launch_bounds__(256)
void mfma_gemm_kernel(const unsigned short* __restrict__ A, const unsigned short* __restrict__ Bt,
                      const float* __restrict__ bias, const float* __restrict__ bias2,
                      const float* __restrict__ bias3, const float* __restrict__ extra,
                      float* __restrict__ C, unsigned short* __restrict__ Cbf,
                      int M, int N, int K,
                      long long sA, long long sB, long long sC)
{
  constexpr int NTt = (BM == 128) ? 4 : 2;   // 16-wide n-fragments per wave
  __shared__ unsigned short As[BM][4][8];
  __shared__ unsigned short Bs[128][4][8];
  const int tid = threadIdx.x;
  const int l = tid & 63, w = tid >> 6;
  const int wm = (BM == 128) ? (w & 1) * 64 : 0;
  const int wn = (BM == 128) ? (w >> 1) * 64 : w * 32;
  const int m0 = blockIdx.y * BM, n0 = blockIdx.x * 128;
  const unsigned short* Ap = A + (long long)blockIdx.z * sA;
  const unsigned short* Bp = Bt + (long long)blockIdx.z * sB;

  f32x4v acc[4][NTt];
  #pragma unroll
  for (int mt = 0; mt < 4; mt++)
    #pragma unroll
    for (int nt = 0; nt < NTt; nt++) acc[mt][nt] = {0.f, 0.f, 0.f, 0.f};

  const int c_ = l >> 4, rm = l & 15;
  int rrB[2], ggB[2];
  #pragma unroll
  for (int j = 0; j < 2; j++) {
    const int chunk = w * 128 + j * 64 + l;
    rrB[j] = chunk >> 2;
    ggB[j] = (chunk & 3) ^ (rrB[j] & 3);
  }
  int rrA = 0, ggA = 0;
  if constexpr (BM == 64) {
    const int chunkA = w * 64 + l;
    rrA = chunkA >> 2;
    ggA = (chunkA & 3) ^ (rrA & 3);
  }

  for (int k0 = 0; k0 < K; k0 += 32) {
    __syncthreads();
    if constexpr (BM == 128) {
      #pragma unroll
      for (int j = 0; j < 2; j++) {
        async16(Ap + (size_t)(m0 + rrB[j]) * K + k0 + ggB[j] * 8,
                &As[0][0][0] + (size_t)(w * 128 + j * 64) * 8);
        async16(Bp + (size_t)(n0 + rrB[j]) * K + k0 + ggB[j] * 8,
                &Bs[0][0][0] + (size_t)(w * 128 + j * 64) * 8);
      }
    } else {
      async16(Ap + (size_t)(m0 + rrA) * K + k0 + ggA * 8,
              &As[0][0][0] + (size_t)(w * 64) * 8);
      #pragma unroll
      for (int j = 0; j < 2; j++)
        async16(Bp + (size_t)(n0 + rrB[j]) * K + k0 + ggB[j] * 8,
                &Bs[0][0][0] + (size_t)(w * 128 + j * 64) * 8);
    }
    __syncthreads();   // drains vmcnt before barrier

    frag af[4], bfr[NTt];
    #pragma unroll
    for (int mt = 0; mt < 4; mt++)
      af[mt] = *(const frag*)&As[wm + mt * 16 + rm][c_ ^ (rm & 3)][0];
    #pragma unroll
    for (int nt = 0; nt < NTt; nt++)
      bfr[nt] = *(const frag*)&Bs[wn + nt * 16 + rm][c_ ^ (rm & 3)][0];
    #pragma unroll
    for (int mt = 0; mt < 4; mt++)
      #pragma unroll
      for (int nt = 0; nt < NTt; nt++)
        acc[mt][nt] = __builtin_amdgcn_mfma_f32_16x16x32_bf16(af[mt], bfr[nt], acc[mt][nt], 0, 0, 0);
  }

  float* Cp = C + (long long)blockIdx.z * sC;
  unsigned short* Cbp = Cbf + (long long)blockIdx.z * sC;
  #pragma unroll
  for (int mt = 0; mt < 4; mt++) {
    #pragma unroll
    for (int nt = 0; nt < NTt; nt++) {
      const int mq = m0 + wm + mt * 16 + c_ * 4;   // quad-base row (i = 0..3 below)
      const int n  = n0 + wn + nt * 16 + rm;       // C/D: col=lane&15
      if constexpr (EPI == EPI_QKV) {
        // n in [0,1024): q (fp32) | [1024,2048): k (fp32) | [2048,3072): V^T bf16
        const float* bp = (n < 1024) ? bias : ((n < 2048) ? bias2 : bias3);
        const float bv_ = ldf(bp + (n & 1023));
        const float r0 = acc[mt][nt][0] + bv_;
        const float r1 = acc[mt][nt][1] + bv_;
        const float r2 = acc[mt][nt][2] + bv_;
        const float r3 = acc[mt][nt][3] + bv_;
        if (n < 2048) {
          float* dst = Cp + (size_t)(n >> 10) * TD + (size_t)mq * Dc + (n & 1023);
          dst[0] = r0; dst[Dc] = r1; dst[2 * Dc] = r2; dst[3 * Dc] = r3;
        } else {
          ushort4 o;
          o.x = f2b(r0); o.y = f2b(r1); o.z = f2b(r2); o.w = f2b(r3);
          *(ushort4*)(Cbp + (size_t)(mq >> 11) * ((size_t)Lc * Dc)
                      + (size_t)(n - 2048) * Lc + (mq & (Lc - 1))) = o;
        }
      } else {
        #pragma unroll
        for (int i = 0; i < 4; i++) {
          const int m = mq + i;                     // C/D: row=(lane>>4)*4+reg
          float r = acc[mt][nt][i];
          if constexpr (EPI == EPI_BIAS || EPI == EPI_GELU || EPI == EPI_ADD || EPI == EPI_ADDROW0)
            r += ldf(bias + n);
          if constexpr (EPI == EPI_BIAS_ROW) r += ldf(bias + m);
          if constexpr (EPI == EPI_GELU)
            r = 0.5f * r * (1.0f + erff(r * 0.70710678118654752f));
          if constexpr (EPI == EPI_ADD) r += extra[(size_t)m * N + n];
          if constexpr (EPI == EPI_ADDROW0) r += extra[(size_t)(m >> 11) * ((size_t)Lc * Dc) + n];
          if constexpr (OUTBOTH) { Cp[(size_t)m * N + n] = r; Cbp[(size_t)m * N + n] = f2b(r); }
          else if constexpr (OUTBF) Cbp[(size_t)m * N + n] = f2b(r);
          else                      Cp[(size_t)m * N + n] = r;
        }
      }
    }
  }
}

// ---------- RoPE table fill ----------
__global__ __launch_bounds__(256)
void pe_fill_kernel(float* __restrict__ pet)
{
  const int gid = blockIdx.x * 256 + threadIdx.x;  // Lc*64
  const int l = gid >> 6, t = gid & 63;
  const int j = t & 31;
  const float wj = exp2f(-(float)j * (13.2877123795494f / 32.0f));
  const float ang = (float)l * wj;
  pet[gid] = (t < 32) ? cosf(ang) : sinf(ang);
}

// ---------- fused RoPE for Q and K: fp32 in, bf16 out ----------
__global__ __launch_bounds__(256)
void rope2_kernel(const float* __restrict__ Qi, const float* __restrict__ Ki,
                  const float* __restrict__ pet,
                  unsigned short* __restrict__ Qo, unsigned short* __restrict__ Ko)
{
  int gid = blockIdx.x * 256 + threadIdx.x;  // 2*NT*Hc
  const int sel = gid >= NT * Hc;
  if (sel) gid -= NT * Hc;
  const float* X = sel ? Ki : Qi;
  unsigned short* O = sel ? Ko : Qo;
  const int h = gid & (Hc - 1);
  const int token = gid >> 4;
  const int l = token & (Lc - 1);
  const float* p = X + (size_t)token * Dc + h * HDc;
  unsigned short* po = O + (size_t)token * Dc + h * HDc;
  const float* pr = pet + l * 64;
  float x[64], out[64];
  #pragma unroll
  for (int i = 0; i < 16; i++) *(float4*)&x[4*i] = *(const float4*)&p[4*i];
  #pragma unroll
  for (int u = 0; u < 32; u++) {
    const int base = (u < 16) ? (2 * u) : (32 + 2 * (u - 16));
    const float c = pr[base], s = pr[base + 1];
    out[u]      = x[2*u] * c - x[2*u+1] * s;
    out[32 + u] = x[2*u] * s + x[2*u+1] * c;
  }
  #pragma unroll
  for (int i = 0; i < 16; i++) {
    ushort4 o;
    o.x = f2b(out[4*i+0]); o.y = f2b(out[4*i+1]);
    o.z = f2b(out[4*i+2]); o.w = f2b(out[4*i+3]);
    *(ushort4*)&po[4*i] = o;
  }
}

// ---------- MFMA flash attention v3 ----------
// One block = 128 q-rows x one (b,h). 4 waves x 32 q-rows.
// S^T = K*Q^T (rows=k, cols=q): softmax row at fixed lane (2-shfl reduce),
// P exits with 4 consecutive k per reg quad -> packed ushort4 stores into Ps.
// PV: O = P*V^T with P natural A-layout, Vt natural [d][k] B-layout.
// All staging via global_load_lds; bank swizzle on the global source index.
__global__ __launch_bounds__(256)
void flash_attn_mfma_kernel(const unsigned short* __restrict__ Q,
                            const unsigned short* __restrict__ K,
                            const unsigned short* __restrict__ VT,
                            unsigned short* __restrict__ O)
{
  __shared__ unsigned short Qs[128][8][8];
  __shared__ unsigned short Ks[64][8][8];
  __shared__ unsigned short Vt[64][8][8];
  __shared__ unsigned short Ps[128][72];
  const int tid = threadIdx.x;
  const int l = tid & 63, w = tid >> 6;
  const int lg = l >> 4, lm = l & 15;
  const int q0 = blockIdx.x * 128;
  const int bh = blockIdx.y;
  const int b = bh >> 4, h = bh & 15;
  const size_t rowbase = (size_t)b * Lc;
  const size_t vbase = (size_t)b * Lc * Dc;
  const int dbase = h * 64;
  const float sc1 = 0.125f * 1.44269504f;                  // scale * log2(e)
  const float sl2 = exp2f(-0.5f * (float)h) * 1.44269504f; // slope * log2(e)

  // ---- stage Q (128 rows x 64 d = 1024 chunks) ----
  #pragma unroll
  for (int j = 0; j < 4; j++) {
    const int chunk = (w * 4 + j) * 64 + l;
    const int r = chunk >> 3, gsrc = (chunk & 7) ^ (r & 7);
    async16(Q + (rowbase + q0 + r) * Dc + dbase + gsrc * 8,
            &Qs[0][0][0] + (size_t)chunk * 8);
  }
  __syncthreads();
  frag qf[2][2];
  #pragma unroll
  for (int qt = 0; qt < 2; qt++)
    #pragma unroll
    for (int s = 0; s < 2; s++)
      qf[qt][s] = *(const frag*)&Qs[w * 32 + qt * 16 + lm][(s * 4 + lg) ^ (lm & 7)][0];

  float m_i[2], l_i[2];
  f32x4v acc_o[2][4];
  #pragma unroll
  for (int qt = 0; qt < 2; qt++) {
    m_i[qt] = -3.0e38f; l_i[qt] = 0.f;
    #pragma unroll
    for (int dt = 0; dt < 4; dt++) acc_o[qt][dt] = {0.f, 0.f, 0.f, 0.f};
  }

  for (int k0 = 0; k0 < Lc; k0 += 64) {
    __syncthreads();   // prior tile reads complete
    #pragma unroll
    for (int j = 0; j < 2; j++) {
      const int chunk = (w * 2 + j) * 64 + l;
      const int r = chunk >> 3, gsrc = (chunk & 7) ^ (r & 7);
      async16(K + (rowbase + k0 + r) * Dc + dbase + gsrc * 8,
              &Ks[0][0][0] + (size_t)chunk * 8);
      async16(VT + vbase + (size_t)(dbase + r) * Lc + k0 + gsrc * 8,
              &Vt[0][0][0] + (size_t)chunk * 8);
    }
    __syncthreads();

    // ---- S^T = K Q^T : rows k (64), cols q (32 of this wave) ----
    f32x4v st[2][4];
    #pragma unroll
    for (int qt = 0; qt < 2; qt++)
      #pragma unroll
      for (int kt = 0; kt < 4; kt++) st[qt][kt] = {0.f, 0.f, 0.f, 0.f};
    #pragma unroll
    for (int kt = 0; kt < 4; kt++) {
      #pragma unroll
      for (int s = 0; s < 2; s++) {
        frag kf = *(const frag*)&Ks[kt * 16 + lm][(s * 4 + lg) ^ (lm & 7)][0];
        #pragma unroll
        for (int qt = 0; qt < 2; qt++)
          st[qt][kt] = __builtin_amdgcn_mfma_f32_16x16x32_bf16(kf, qf[qt][s], st[qt][kt], 0, 0, 0);
      }
    }

    // ---- softmax (base-2); lane's q = qt*16+lm; k = kt*16 + lg*4 + i ----
    #pragma unroll
    for (int qt = 0; qt < 2; qt++) {
      const float qg = (float)(q0 + w * 32 + qt * 16 + lm);
      float sv[4][4], tmax = -3.0e38f;
      #pragma unroll
      for (int kt = 0; kt < 4; kt++)
        #pragma unroll
        for (int i = 0; i < 4; i++) {
          const float kg = (float)(k0 + kt * 16 + lg * 4 + i);
          const float v = st[qt][kt][i] * sc1 + sl2 * fmaxf(qg - kg, 0.0f);
          sv[kt][i] = v; tmax = fmaxf(tmax, v);
        }
      tmax = fmaxf(tmax, __shfl_xor(tmax, 16, 64));
      tmax = fmaxf(tmax, __shfl_xor(tmax, 32, 64));
      const float mnew = fmaxf(m_i[qt], tmax);
      const float alpha = exp2f(m_i[qt] - mnew);
      m_i[qt] = mnew;
      float rsum = 0.f;
      const int qrow = w * 32 + qt * 16 + lm;
      #pragma unroll
      for (int kt = 0; kt < 4; kt++) {
        const float p0 = exp2f(sv[kt][0] - mnew), p1 = exp2f(sv[kt][1] - mnew);
        const float p2 = exp2f(sv[kt][2] - mnew), p3 = exp2f(sv[kt][3] - mnew);
        rsum += (p0 + p1) + (p2 + p3);
        ushort4 pk4;
        pk4.x = f2b(p0); pk4.y = f2b(p1); pk4.z = f2b(p2); pk4.w = f2b(p3);
        *(ushort4*)&Ps[qrow][kt * 16 + lg * 4] = pk4;   // 4 consecutive k
      }
      rsum += __shfl_xor(rsum, 16, 64);
      rsum += __shfl_xor(rsum, 32, 64);
      l_i[qt] = l_i[qt] * alpha + rsum;
      float aO[4];
      #pragma unroll
      for (int i = 0; i < 4; i++) aO[i] = __shfl(alpha, lg * 4 + i, 64);
      #pragma unroll
      for (int dt = 0; dt < 4; dt++)
        #pragma unroll
        for (int i = 0; i < 4; i++) acc_o[qt][dt][i] *= aO[i];
    }

    // ---- O += P V (Ps rows wave-private; same-wave DS order suffices) ----
    #pragma unroll
    for (int c = 0; c < 2; c++) {
      frag ap[2];
      #pragma unroll
      for (int qt = 0; qt < 2; qt++)
        ap[qt] = *(const frag*)&Ps[w * 32 + qt * 16 + lm][c * 32 + lg * 8];
      #pragma unroll
      for (int dt = 0; dt < 4; dt++) {
        frag bv = *(const frag*)&Vt[dt * 16 + lm][(c * 4 + lg) ^ (lm & 7)][0];
        #pragma unroll
        for (int qt = 0; qt < 2; qt++)
          acc_o[qt][dt] = __builtin_amdgcn_mfma_f32_16x16x32_bf16(ap[qt], bv, acc_o[qt][dt], 0, 0, 0);
      }
    }
  }

  // ---- epilogue: normalize, bounce through Ps, coalesced store ----
  #pragma unroll
  for (int qt = 0; qt < 2; qt++) {
    float lO[4];
    #pragma unroll
    for (int i = 0; i < 4; i++) lO[i] = 1.0f / __shfl(l_i[qt], lg * 4 + i, 64);
    #pragma unroll
    for (int dt = 0; dt < 4; dt++)
      #pragma unroll
      for (int i = 0; i < 4; i++)
        Ps[w * 32 + qt * 16 + lg * 4 + i][dt * 16 + lm] = f2b(acc_o[qt][dt][i] * lO[i]);
  }
  __syncthreads();
  #pragma unroll
  for (int j = 0; j < 4; j++) {
    const int chunk = (w * 4 + j) * 64 + l;
    const int r = chunk >> 3, g = chunk & 7;
    alignas(16) unsigned short tmp[8];
    #pragma unroll
    for (int t = 0; t < 8; t++) tmp[t] = Ps[r][g * 8 + t];
    *(uint4*)(O + (rowbase + q0 + r) * Dc + dbase + g * 8) = *(uint4*)tmp;
  }
}

// ---------- fused: mem1 = RES + ln(X;n1) -> fp32; hln = ln(mem1;cln) -> bf16 ----
__global__ __launch_bounds__(256)
void ln_res_cln_kernel(const float* __restrict__ X, const float* __restrict__ RES,
                       const float* __restrict__ g1, const float* __restrict__ b1,
                       const float* __restrict__ g2, const float* __restrict__ b2,
                       float* __restrict__ OUT1, unsigned short* __restrict__ OUT2)
{
  __shared__ float red4[4];
  const int row = blockIdx.x, tid = threadIdx.x;
  const size_t base = (size_t)row * Dc + tid * 4;
  const float4 xv = *(const float4*)(X + base);
  float s = xv.x + xv.y + xv.z + xv.w;
  s = block_sum(s, red4);
  const float mean = s * (1.0f / Dc);
  const float d0 = xv.x-mean, d1 = xv.y-mean, d2 = xv.z-mean, d3 = xv.w-mean;
  float ss = d0*d0 + d1*d1 + d2*d2 + d3*d3;
  ss = block_sum(ss, red4);
  const float rstd = rsqrtf(ss * (1.0f / Dc) + 1e-5f);
  const int c = tid * 4;
  const float4 rv = *(const float4*)(RES + base);
  float y0 = rv.x + d0*rstd*ldf(g1+c+0) + ldf(b1+c+0);
  float y1 = rv.y + d1*rstd*ldf(g1+c+1) + ldf(b1+c+1);
  float y2 = rv.z + d2*rstd*ldf(g1+c+2) + ldf(b1+c+2);
  float y3 = rv.w + d3*rstd*ldf(g1+c+3) + ldf(b1+c+3);
  *(float4*)(OUT1 + base) = make_float4(y0, y1, y2, y3);
  float s2 = y0 + y1 + y2 + y3;
  s2 = block_sum(s2, red4);
  const float mean2 = s2 * (1.0f / Dc);
  const float e0 = y0-mean2, e1 = y1-mean2, e2 = y2-mean2, e3 = y3-mean2;
  float ss2 = e0*e0 + e1*e1 + e2*e2 + e3*e3;
  ss2 = block_sum(ss2, red4);
  const float rstd2 = rsqrtf(ss2 * (1.0f / Dc) + 1e-5f);
  ushort4 o;
  o.x = f2b(e0*rstd2*ldf(g2+c+0) + ldf(b2+c+0));
  o.y = f2b(e1*rstd2*ldf(g2+c+1) + ldf(b2+c+1));
  o.z = f2b(e2*rstd2*ldf(g2+c+2) + ldf(b2+c+2));
  o.w = f2b(e3*rstd2*ldf(g2+c+3) + ldf(b2+c+3));
  *(ushort4*)(OUT2 + base) = o;
}

__global__ __launch_bounds__(256)   // OUT = ln(X + Y)
void ln_sum_kernel(const float* __restrict__ X, const float* __restrict__ Y,
                   const float* __restrict__ g, const float* __restrict__ be,
                   float* __restrict__ OUT)
{
  __shared__ float red4[4];
  const int row = blockIdx.x, tid = threadIdx.x;
  const size_t base = (size_t)row * Dc + tid * 4;
  const float4 xv = *(const float4*)(X + base);
  const float4 yv = *(const float4*)(Y + base);
  const float x0 = xv.x+yv.x, x1 = xv.y+yv.y, x2 = xv.z+yv.z, x3 = xv.w+yv.w;
  float s = x0 + x1 + x2 + x3;
  s = block_sum(s, red4);
  const float mean = s * (1.0f / Dc);
  const float d0 = x0-mean, d1 = x1-mean, d2 = x2-mean, d3 = x3-mean;
  float ss = d0*d0 + d1*d1 + d2*d2 + d3*d3;
  ss = block_sum(ss, red4);
  const float rstd = rsqrtf(ss * (1.0f / Dc) + 1e-5f);
  const int c = tid * 4;
  float4 o;
  o.x = d0*rstd*ldf(g+c+0) + ldf(be+c+0);
  o.y = d1*rstd*ldf(g+c+1) + ldf(be+c+1);
  o.z = d2*rstd*ldf(g+c+2) + ldf(be+c+2);
  o.w = d3*rstd*ldf(g+c+3) + ldf(be+c+3);
  *(float4*)(OUT + base) = o;
}

// ---------- GLU ----------
__global__ __launch_bounds__(256)
void glu_kernel(const float* __restrict__ H1, float* __restrict__ HG)
{
  const int gid = blockIdx.x * 256 + threadIdx.x;
  const int t = gid >> 8;
  const int c4 = (gid & 255) * 4;
  const float* p = H1 + (size_t)t * (2 * Dc);
  const float4 a = *(const float4*)(p + c4);
  const float4 gg = *(const float4*)(p + Dc + c4);
  float4 o;
  o.x = a.x / (1.0f + expf(-gg.x));
  o.y = a.y / (1.0f + expf(-gg.y));
  o.z = a.z / (1.0f + expf(-gg.z));
  o.w = a.w / (1.0f + expf(-gg.w));
  *(float4*)(HG + (size_t)t * Dc + c4) = o;
}

// ---------- depthwise conv K=5 (+bias, bn-scale, hardswish), bf16 out ----------
__global__ __launch_bounds__(256)
void dwconv_bf16_kernel(const float* __restrict__ HG, const float* __restrict__ w,
                        const float* __restrict__ wb, const float* __restrict__ gn,
                        const float* __restrict__ bb, unsigned short* __restrict__ OUT)
{
  const int gid = blockIdx.x * 256 + threadIdx.x;
  const int d = gid & (Dc - 1);
  const int l = (gid >> 10) & (Lc - 1);
  const int b = gid >> 21;
  const size_t rowb = (size_t)b * Lc;
  float acc = ldf(wb + d);
  #pragma unroll
  for (int s = 0; s < 5; s++) {
    const int lp = l + 2 - s;
    if (lp >= 0 && lp < Lc)
      acc += ldf(w + d * 5 + s) * HG[((rowb + lp) << 10) + d];
  }
  const float rs = rsqrtf(1.0f + 1e-5f);
  const float t = acc * rs * ldf(gn + d) + ldf(bb + d);
  OUT[gid] = f2b(t * fminf(fmaxf(t + 3.0f, 0.0f), 6.0f) * (1.0f / 6.0f));
}

// =====================================================================
extern "C" void kernel_launch(void* const* d_in, const int* in_sizes, int n_in,
                              void* d_out, int out_size, void* d_ws, size_t ws_size,
                              hipStream_t stream) {
  (void)in_sizes; (void)n_in; (void)out_size; (void)ws_size;
  const float* mem    = (const float*)d_in[0];
  const float* wq     = (const float*)d_in[1];
  const float* bq     = (const float*)d_in[2];
  const float* wk     = (const float*)d_in[3];
  const float* bk     = (const float*)d_in[4];
  const float* wv     = (const float*)d_in[5];
  const float* bv     = (const float*)d_in[6];
  const float* wo     = (const float*)d_in[7];
  const float* bo     = (const float*)d_in[8];
  const float* n1g    = (const float*)d_in[9];
  const float* n1b    = (const float*)d_in[10];
  const float* clng   = (const float*)d_in[11];
  const float* clnb   = (const float*)d_in[12];
  const float* pw1w   = (const float*)d_in[13];
  const float* pw1b   = (const float*)d_in[14];
  const float* dww    = (const float*)d_in[15];
  const float* dwb    = (const float*)d_in[16];
  const float* bng    = (const float*)d_in[17];
  const float* bnb    = (const float*)d_in[18];
  const float* pw2w   = (const float*)d_in[19];
  const float* pw2b   = (const float*)d_in[20];
  const float* projw  = (const float*)d_in[21];
  const float* projb  = (const float*)d_in[22];
  const float* proj2w = (const float*)d_in[23];
  const float* proj2b = (const float*)d_in[24];
  const float* lin1w  = (const float*)d_in[25];
  const float* lin1b  = (const float*)d_in[26];
  const float* lin2w  = (const float*)d_in[27];
  const float* lin2b  = (const float*)d_in[28];
  const float* n3g    = (const float*)d_in[29];
  const float* n3b    = (const float*)d_in[30];
  float* out = (float*)d_out;

  char* base = (char*)d_ws;
  float* qb   = (float*)base;          // q fp32 -> tgt2 fp32
  float* kb   = qb + TD;               // k fp32 -> mem1
  float* big1 = kb + TD;               // h1 lo -> mem2 fp32
  float* big2 = big1 + TD;             // h1 hi -> conv_out
  float* ob   = big2 + TD;             // hg -> ffout
  unsigned short* abf  = (unsigned short*)(base + 5 * TD * 4);  // bf16 hub
  unsigned short* qbf  = abf + TD;     // rope-q -> mem2 bf16
  unsigned short* kbf  = qbf + TD;
  unsigned short* vtb  = kbf + TD;     // V^T bf16  [b][1024 d][2048 l]
  unsigned short* m1T  = vtb + TD;
  unsigned short* ffbbf= m1T + TD;     // NT*FF = 4*TD shorts
  unsigned short* wt   = ffbbf + 4 * TD;
  unsigned short* wqT    = wt;            // [1024][1024] } contiguous => [3072][1024] fused QKV B^T
  unsigned short* wkT    = wqT + MEG;
  unsigned short* wvT    = wkT + MEG;
  unsigned short* woT    = wvT + MEG;
  unsigned short* pw1T   = woT + MEG;     // [2048][1024]
  unsigned short* pw2T   = pw1T + 2*MEG;  // [1024][1024]
  unsigned short* proj2T = pw2T + MEG;    // [1024][1024]
  unsigned short* projwT = proj2T + MEG;  // [2048][2048]
  unsigned short* lin1T  = projwT + 4*MEG;// [4096][1024]
  unsigned short* lin2T  = lin1T + 4*MEG; // [1024][4096]
  float* pet = (float*)(lin2T + 4*MEG);   // [2048][64] rope table

  const dim3 blk(256);
  const long long LD = (long long)Lc * Dc;

  // ---- fused weight transposes + rope table ----
  TPack tp;
  const float* tin[10]  = {wq, wk, wv, wo, pw1w, pw2w, proj2w, projw, lin1w, lin2w};
  unsigned short* tout[10] = {wqT, wkT, wvT, woT, pw1T, pw2T, proj2T, projwT, lin1T, lin2T};
  const int tR[10] = {1024,1024,1024,1024,1024,1024,1024,2048,1024,4096};
  const int tC[10] = {1024,1024,1024,1024,2048,1024,1024,2048,4096,1024};
  int startAcc = 0;
  for (int i = 0; i < 10; i++) {
    tp.in[i] = tin[i]; tp.out[i] = tout[i];
    tp.R[i] = tR[i]; tp.C[i] = tC[i]; tp.tx[i] = tC[i] / 64;
    tp.start[i] = startAcc;
    startAcc += (tR[i] / 64) * (tC[i] / 64);
  }
  fused_transpose_kernel<<<dim3(startAcc), blk, 0, stream>>>(tp);
  pe_fill_kernel<<<dim3(Lc * 64 / 256), blk, 0, stream>>>(pet);

  // ---- attention ----
  convert_bf16_kernel<<<dim3((unsigned)(TD/1024)),blk,0,stream>>>(mem, abf);
  // fused QKV: N=3072, q->qb fp32, k->kb fp32, V->vtb transposed bf16 directly
  mfma_gemm_kernel<128,EPI_QKV,false,false><<<dim3(24,32,1),blk,0,stream>>>(
      abf, wqT, bq, bk, bv, nullptr, qb, vtb, NT, 3*Dc, Dc, 0, 0, 0);
  rope2_kernel<<<dim3(2*NT*Hc/256),blk,0,stream>>>(qb, kb, pet, qbf, kbf);
  flash_attn_mfma_kernel<<<dim3(Lc/128, Bc*Hc),blk,0,stream>>>(qbf,kbf,vtb,abf);
  mfma_gemm_kernel<64,EPI_BIAS,false,false><<<dim3(8,64,1),blk,0,stream>>>(
      abf,woT,bo,nullptr,nullptr,nullptr,qb,nullptr,NT,Dc,Dc,0,0,0);
  // mem1 (fp32 -> kb) and ln(mem1) (bf16 -> abf) in one pass
  ln_res_cln_kernel<<<dim3(NT),blk,0,stream>>>(qb, mem, n1g, n1b, clng, clnb, kb, abf);

  // ---- conv block ----
  mfma_gemm_kernel<128,EPI_BIAS,false,false><<<dim3(16,32,1),blk,0,stream>>>(
      abf,pw1T,pw1b,nullptr,nullptr,nullptr,big1,nullptr,NT,2*Dc,Dc,0,0,0);
  glu_kernel<<<dim3((unsigned)(TD/4/256)),blk,0,stream>>>(big1, ob);
  dwconv_bf16_kernel<<<dim3((unsigned)(TD/256)),blk,0,stream>>>(ob, dww, dwb, bng, bnb, abf);
  mfma_gemm_kernel<64,EPI_ADDROW0,false,false><<<dim3(8,64,1),blk,0,stream>>>(
      abf,pw2T,pw2b,nullptr,nullptr,kb,big2,nullptr,NT,Dc,Dc,0,0,0);

  // ---- proj path ----
  transpose_convert_kernel<<<dim3(16,32,2),blk,0,stream>>>(kb, m1T, 2048, 1024, LD, LD);
  mfma_gemm_kernel<64,EPI_BIAS_ROW,true,false><<<dim3(8,32,2),blk,0,stream>>>(
      projwT,m1T,projb,nullptr,nullptr,nullptr,nullptr,abf,Lc,Dc,Lc,0,LD,LD);
  // mem2 = proj@proj2 + conv_out: fp32 -> big1 AND bf16 -> qbf (feeds lin1)
  mfma_gemm_kernel<64,EPI_ADD,false,true><<<dim3(8,64,1),blk,0,stream>>>(
      abf,proj2T,proj2b,nullptr,nullptr,big2,big1,qbf,NT,Dc,Dc,0,0,0);

  // ---- feed-forward ----
  mfma_gemm_kernel<128,EPI_GELU,true,false><<<dim3(32,32,1),blk,0,stream>>>(
      qbf,lin1T,lin1b,nullptr,nullptr,nullptr,nullptr,ffbbf,NT,FFc,Dc,0,0,0);
  mfma_gemm_kernel<64,EPI_BIAS,false,false><<<dim3(8,64,1),blk,0,stream>>>(
      ffbbf,lin2T,lin2b,nullptr,nullptr,nullptr,ob,nullptr,NT,Dc,FFc,0,0,0);

  // ---- final: out = ln(mem2 + ffout) ----
  ln_sum_kernel<<<dim3(NT),blk,0,stream>>>(big1, ob, n3g, n3b, out);
}

// Round 2
// 701.082 us; speedup vs baseline: 1.0363x; 1.0363x over previous
//
#include <hip/hip_runtime.h>
#include <hip/hip_bf16.h>
#include <math.h>

constexpr int Bc = 2, Lc = 2048, Dc = 1024, Hc = 16, HDc = 64, FFc = 4096;
constexpr int NT = Bc * Lc;              // 4096 tokens
constexpr size_t TD = (size_t)NT * Dc;   // 4194304 elements per [B,L,D] tensor
constexpr size_t MEG = 1024 * 1024;

__device__ __forceinline__ float ldf(const float* p) { return *p; }
__device__ __forceinline__ unsigned short f2b(float f) {
  __hip_bfloat16 h = __float2bfloat16(f);
  return *reinterpret_cast<unsigned short*>(&h);
}

using frag   = __attribute__((ext_vector_type(8))) short;   // 8 bf16 (4 VGPRs)
using f32x4v = __attribute__((ext_vector_type(4))) float;   // MFMA C/D

// async global -> LDS, 16B per lane; LDS dest = wave-uniform base + lane*16
__device__ __forceinline__ void async16(const unsigned short* g, unsigned short* l) {
  __builtin_amdgcn_global_load_lds(
      (const __attribute__((address_space(1))) unsigned int*)g,
      (__attribute__((address_space(3))) unsigned int*)l, 16, 0, 0);
}

// ---------- block reductions (blockDim.x == 256 = 4 waves) ----------
__device__ __forceinline__ float block_sum(float v, float* red) {
  const int lane = threadIdx.x & 63, w = threadIdx.x >> 6;
  #pragma unroll
  for (int o = 32; o > 0; o >>= 1) v += __shfl_down(v, o, 64);
  __syncthreads();
  if (lane == 0) red[w] = v;
  __syncthreads();
  return red[0] + red[1] + red[2] + red[3];
}

// ---------- fp32 -> bf16 convert ----------
__global__ __launch_bounds__(256)
void convert_bf16_kernel(const float* __restrict__ IN, unsigned short* __restrict__ OUT)
{
  const size_t gid = (size_t)blockIdx.x * 256 + threadIdx.x;
  const float4 v = *(const float4*)(IN + gid * 4);
  ushort4 o;
  o.x = f2b(v.x); o.y = f2b(v.y); o.z = f2b(v.z); o.w = f2b(v.w);
  *(ushort4*)(OUT + gid * 4) = o;
}

// ---------- fp32 [R,C] -> bf16 [C,R] transpose-convert (z-batched) ----------
__global__ __launch_bounds__(256)
void transpose_convert_kernel(const float* __restrict__ IN, unsigned short* __restrict__ OUT,
                              int R, int C, long long sIn, long long sOut)
{
  __shared__ float tile[64][65];
  const int t = threadIdx.x;
  const float* in = IN + (long long)blockIdx.z * sIn;
  unsigned short* out = OUT + (long long)blockIdx.z * sOut;
  const int r0 = blockIdx.y * 64, c0 = blockIdx.x * 64;
  #pragma unroll
  for (int i = 0; i < 4; i++) {
    const int r = (t >> 4) + i * 16, c4 = (t & 15) * 4;
    const float4 v = *(const float4*)(in + (size_t)(r0 + r) * C + c0 + c4);
    tile[r][c4+0] = v.x; tile[r][c4+1] = v.y; tile[r][c4+2] = v.z; tile[r][c4+3] = v.w;
  }
  __syncthreads();
  #pragma unroll
  for (int i = 0; i < 4; i++) {
    const int cc = (t >> 4) + i * 16, rr4 = (t & 15) * 4;
    ushort4 o;
    o.x = f2b(tile[rr4+0][cc]); o.y = f2b(tile[rr4+1][cc]);
    o.z = f2b(tile[rr4+2][cc]); o.w = f2b(tile[rr4+3][cc]);
    *(ushort4*)(out + (size_t)(c0 + cc) * R + r0 + rr4) = o;
  }
}

// ---------- fused weight transposes: 10 segments in one launch ----------
struct TPack {
  const float* in[10]; unsigned short* out[10];
  int R[10], C[10], tx[10], start[10];
};
__global__ __launch_bounds__(256)
void fused_transpose_kernel(TPack p)
{
  __shared__ float tile[64][65];
  const int bid = blockIdx.x;
  int s = 0;
  #pragma unroll
  for (int i = 1; i < 10; i++) s = (bid >= p.start[i]) ? i : s;
  const float* in = p.in[s];
  unsigned short* out = p.out[s];
  const int R = p.R[s], C = p.C[s];
  const int local = bid - p.start[s];
  const int bx = local % p.tx[s], by = local / p.tx[s];
  const int r0 = by * 64, c0 = bx * 64;
  const int t = threadIdx.x;
  #pragma unroll
  for (int i = 0; i < 4; i++) {
    const int r = (t >> 4) + i * 16, c4 = (t & 15) * 4;
    const float4 v = *(const float4*)(in + (size_t)(r0 + r) * C + c0 + c4);
    tile[r][c4+0] = v.x; tile[r][c4+1] = v.y; tile[r][c4+2] = v.z; tile[r][c4+3] = v.w;
  }
  __syncthreads();
  #pragma unroll
  for (int i = 0; i < 4; i++) {
    const int cc = (t >> 4) + i * 16, rr4 = (t & 15) * 4;
    ushort4 o;
    o.x = f2b(tile[rr4+0][cc]); o.y = f2b(tile[rr4+1][cc]);
    o.z = f2b(tile[rr4+2][cc]); o.w = f2b(tile[rr4+3][cc]);
    *(ushort4*)(out + (size_t)(c0 + cc) * R + r0 + rr4) = o;
  }
}

// ---------- MFMA bf16 GEMM, global_load_lds staging ----------
// C[m,n] = sum_k A[m,k] * Bt[n,k]. Tile BM x 128, BK=32.
// BM=128: 4 waves as 2x2 of 64x64, acc[4][4].
// BM=64 : 4 waves as 1x4 of 64x32, acc[4][2] (more blocks for grid-starved shapes).
// LDS [row][granule^(row&3)][8]; bank swizzle applied via the GLOBAL source index.
constexpr int EPI_BIAS = 0, EPI_BIAS_ROW = 1, EPI_GELU = 2, EPI_ADD = 3, EPI_ADDROW0 = 4,
              EPI_QKV = 5;

template<int BM, int EPI, bool OUTBF, bool OUTBOTH>
__global__ __launch_bounds__(256)
void mfma_gemm_kernel(const unsigned short* __restrict__ A, const unsigned short* __restrict__ Bt,
                      const float* __restrict__ bias, const float* __restrict__ bias2,
                      const float* __restrict__ bias3, const float* __restrict__ extra,
                      float* __restrict__ C, unsigned short* __restrict__ Cbf,
                      int M, int N, int K,
                      long long sA, long long sB, long long sC)
{
  constexpr int NTt = (BM == 128) ? 4 : 2;   // 16-wide n-fragments per wave
  __shared__ unsigned short As[BM][4][8];
  __shared__ unsigned short Bs[128][4][8];
  const int tid = threadIdx.x;
  const int l = tid & 63, w = tid >> 6;
  const int wm = (BM == 128) ? (w & 1) * 64 : 0;
  const int wn = (BM == 128) ? (w >> 1) * 64 : w * 32;
  const int m0 = blockIdx.y * BM, n0 = blockIdx.x * 128;
  const unsigned short* Ap = A + (long long)blockIdx.z * sA;
  const unsigned short* Bp = Bt + (long long)blockIdx.z * sB;

  f32x4v acc[4][NTt];
  #pragma unroll
  for (int mt = 0; mt < 4; mt++)
    #pragma unroll
    for (int nt = 0; nt < NTt; nt++) acc[mt][nt] = {0.f, 0.f, 0.f, 0.f};

  const int c_ = l >> 4, rm = l & 15;
  int rrB[2], ggB[2];
  #pragma unroll
  for (int j = 0; j < 2; j++) {
    const int chunk = w * 128 + j * 64 + l;
    rrB[j] = chunk >> 2;
    ggB[j] = (chunk & 3) ^ (rrB[j] & 3);
  }
  int rrA = 0, ggA = 0;
  if constexpr (BM == 64) {
    const int chunkA = w * 64 + l;
    rrA = chunkA >> 2;
    ggA = (chunkA & 3) ^ (rrA & 3);
  }

  for (int k0 = 0; k0 < K; k0 += 32) {
    __syncthreads();
    if constexpr (BM == 128) {
      #pragma unroll
      for (int j = 0; j < 2; j++) {
        async16(Ap + (size_t)(m0 + rrB[j]) * K + k0 + ggB[j] * 8,
                &As[0][0][0] + (size_t)(w * 128 + j * 64) * 8);
        async16(Bp + (size_t)(n0 + rrB[j]) * K + k0 + ggB[j] * 8,
                &Bs[0][0][0] + (size_t)(w * 128 + j * 64) * 8);
      }
    } else {
      async16(Ap + (size_t)(m0 + rrA) * K + k0 + ggA * 8,
              &As[0][0][0] + (size_t)(w * 64) * 8);
      #pragma unroll
      for (int j = 0; j < 2; j++)
        async16(Bp + (size_t)(n0 + rrB[j]) * K + k0 + ggB[j] * 8,
                &Bs[0][0][0] + (size_t)(w * 128 + j * 64) * 8);
    }
    __syncthreads();   // drains vmcnt before barrier

    frag af[4], bfr[NTt];
    #pragma unroll
    for (int mt = 0; mt < 4; mt++)
      af[mt] = *(const frag*)&As[wm + mt * 16 + rm][c_ ^ (rm & 3)][0];
    #pragma unroll
    for (int nt = 0; nt < NTt; nt++)
      bfr[nt] = *(const frag*)&Bs[wn + nt * 16 + rm][c_ ^ (rm & 3)][0];
    #pragma unroll
    for (int mt = 0; mt < 4; mt++)
      #pragma unroll
      for (int nt = 0; nt < NTt; nt++)
        acc[mt][nt] = __builtin_amdgcn_mfma_f32_16x16x32_bf16(af[mt], bfr[nt], acc[mt][nt], 0, 0, 0);
  }

  float* Cp = C + (long long)blockIdx.z * sC;
  unsigned short* Cbp = Cbf + (long long)blockIdx.z * sC;
  #pragma unroll
  for (int mt = 0; mt < 4; mt++) {
    #pragma unroll
    for (int nt = 0; nt < NTt; nt++) {
      const int mq = m0 + wm + mt * 16 + c_ * 4;   // quad-base row (i = 0..3 below)
      const int n  = n0 + wn + nt * 16 + rm;       // C/D: col=lane&15
      if constexpr (EPI == EPI_QKV) {
        // n in [0,1024): q (fp32) | [1024,2048): k (fp32) | [2048,3072): V^T bf16
        const float* bp = (n < 1024) ? bias : ((n < 2048) ? bias2 : bias3);
        const float bv_ = ldf(bp + (n & 1023));
        const float r0 = acc[mt][nt][0] + bv_;
        const float r1 = acc[mt][nt][1] + bv_;
        const float r2 = acc[mt][nt][2] + bv_;
        const float r3 = acc[mt][nt][3] + bv_;
        if (n < 2048) {
          float* dst = Cp + (size_t)(n >> 10) * TD + (size_t)mq * Dc + (n & 1023);
          dst[0] = r0; dst[Dc] = r1; dst[2 * Dc] = r2; dst[3 * Dc] = r3;
        } else {
          ushort4 o;
          o.x = f2b(r0); o.y = f2b(r1); o.z = f2b(r2); o.w = f2b(r3);
          *(ushort4*)(Cbp + (size_t)(mq >> 11) * ((size_t)Lc * Dc)
                      + (size_t)(n - 2048) * Lc + (mq & (Lc - 1))) = o;
        }
      } else {
        #pragma unroll
        for (int i = 0; i < 4; i++) {
          const int m = mq + i;                     // C/D: row=(lane>>4)*4+reg
          float r = acc[mt][nt][i];
          if constexpr (EPI == EPI_BIAS || EPI == EPI_GELU || EPI == EPI_ADD || EPI == EPI_ADDROW0)
            r += ldf(bias + n);
          if constexpr (EPI == EPI_BIAS_ROW) r += ldf(bias + m);
          if constexpr (EPI == EPI_GELU)
            r = 0.5f * r * (1.0f + erff(r * 0.70710678118654752f));
          if constexpr (EPI == EPI_ADD) r += extra[(size_t)m * N + n];
          if constexpr (EPI == EPI_ADDROW0) r += extra[(size_t)(m >> 11) * ((size_t)Lc * Dc) + n];
          if constexpr (OUTBOTH) { Cp[(size_t)m * N + n] = r; Cbp[(size_t)m * N + n] = f2b(r); }
          else if constexpr (OUTBF) Cbp[(size_t)m * N + n] = f2b(r);
          else                      Cp[(size_t)m * N + n] = r;
        }
      }
    }
  }
}

// ---------- RoPE table fill ----------
__global__ __launch_bounds__(256)
void pe_fill_kernel(float* __restrict__ pet)
{
  const int gid = blockIdx.x * 256 + threadIdx.x;  // Lc*64
  const int l = gid >> 6, t = gid & 63;
  const int j = t & 31;
  const float wj = exp2f(-(float)j * (13.2877123795494f / 32.0f));
  const float ang = (float)l * wj;
  pet[gid] = (t < 32) ? cosf(ang) : sinf(ang);
}

// ---------- fused RoPE for Q and K: fp32 in, bf16 out ----------
__global__ __launch_bounds__(256)
void rope2_kernel(const float* __restrict__ Qi, const float* __restrict__ Ki,
                  const float* __restrict__ pet,
                  unsigned short* __restrict__ Qo, unsigned short* __restrict__ Ko)
{
  int gid = blockIdx.x * 256 + threadIdx.x;  // 2*NT*Hc
  const int sel = gid >= NT * Hc;
  if (sel) gid -= NT * Hc;
  const float* X = sel ? Ki : Qi;
  unsigned short* O = sel ? Ko : Qo;
  const int h = gid & (Hc - 1);
  const int token = gid >> 4;
  const int l = token & (Lc - 1);
  const float* p = X + (size_t)token * Dc + h * HDc;
  unsigned short* po = O + (size_t)token * Dc + h * HDc;
  const float* pr = pet + l * 64;
  float x[64], out[64];
  #pragma unroll
  for (int i = 0; i < 16; i++) *(float4*)&x[4*i] = *(const float4*)&p[4*i];
  #pragma unroll
  for (int u = 0; u < 32; u++) {
    const int base = (u < 16) ? (2 * u) : (32 + 2 * (u - 16));
    const float c = pr[base], s = pr[base + 1];
    out[u]      = x[2*u] * c - x[2*u+1] * s;
    out[32 + u] = x[2*u] * s + x[2*u+1] * c;
  }
  #pragma unroll
  for (int i = 0; i < 16; i++) {
    ushort4 o;
    o.x = f2b(out[4*i+0]); o.y = f2b(out[4*i+1]);
    o.z = f2b(out[4*i+2]); o.w = f2b(out[4*i+3]);
    *(ushort4*)&po[4*i] = o;
  }
}

// ---------- MFMA flash attention v4 ----------
// One block = 64 q-rows x one (b,h); grid 32x32 = 1024 blocks -> 4 blocks/CU
// (v3 was 128 rows, 512 blocks, 2/CU, 19% occupancy -> VALU latency exposed).
// 4 waves x 16 q-rows. S^T = K*Q^T; softmax at fixed lane (2-shfl reduce);
// exact rescale-skip when no row max grew (alpha==1 -> identity).
__global__ __launch_bounds__(256)
void flash_attn_mfma_kernel(const unsigned short* __restrict__ Q,
                            const unsigned short* __restrict__ K,
                            const unsigned short* __restrict__ VT,
                            unsigned short* __restrict__ O)
{
  __shared__ unsigned short Qs[64][8][8];
  __shared__ unsigned short Ks[64][8][8];
  __shared__ unsigned short Vt[64][8][8];
  __shared__ unsigned short Ps[64][72];
  const int tid = threadIdx.x;
  const int l = tid & 63, w = tid >> 6;
  const int lg = l >> 4, lm = l & 15;
  const int q0 = blockIdx.x * 64;
  const int bh = blockIdx.y;
  const int b = bh >> 4, h = bh & 15;
  const size_t rowbase = (size_t)b * Lc;
  const size_t vbase = (size_t)b * Lc * Dc;
  const int dbase = h * 64;
  const float sc1 = 0.125f * 1.44269504f;                  // scale * log2(e)
  const float sl2 = exp2f(-0.5f * (float)h) * 1.44269504f; // slope * log2(e)

  // ---- stage Q (64 rows x 64 d = 512 chunks) ----
  #pragma unroll
  for (int j = 0; j < 2; j++) {
    const int chunk = (w * 2 + j) * 64 + l;
    const int r = chunk >> 3, gsrc = (chunk & 7) ^ (r & 7);
    async16(Q + (rowbase + q0 + r) * Dc + dbase + gsrc * 8,
            &Qs[0][0][0] + (size_t)chunk * 8);
  }
  __syncthreads();
  frag qf[2];
  #pragma unroll
  for (int s = 0; s < 2; s++)
    qf[s] = *(const frag*)&Qs[w * 16 + lm][(s * 4 + lg) ^ (lm & 7)][0];

  float m_i = -3.0e38f, l_i = 0.f;
  f32x4v acc_o[4];
  #pragma unroll
  for (int dt = 0; dt < 4; dt++) acc_o[dt] = {0.f, 0.f, 0.f, 0.f};

  for (int k0 = 0; k0 < Lc; k0 += 64) {
    __syncthreads();   // prior tile reads complete
    #pragma unroll
    for (int j = 0; j < 2; j++) {
      const int chunk = (w * 2 + j) * 64 + l;
      const int r = chunk >> 3, gsrc = (chunk & 7) ^ (r & 7);
      async16(K + (rowbase + k0 + r) * Dc + dbase + gsrc * 8,
              &Ks[0][0][0] + (size_t)chunk * 8);
      async16(VT + vbase + (size_t)(dbase + r) * Lc + k0 + gsrc * 8,
              &Vt[0][0][0] + (size_t)chunk * 8);
    }
    __syncthreads();

    // ---- S^T = K Q^T : rows k (64), cols q (16 of this wave) ----
    f32x4v st[4];
    #pragma unroll
    for (int kt = 0; kt < 4; kt++) st[kt] = {0.f, 0.f, 0.f, 0.f};
    __builtin_amdgcn_s_setprio(1);
    #pragma unroll
    for (int kt = 0; kt < 4; kt++) {
      #pragma unroll
      for (int s = 0; s < 2; s++) {
        frag kf = *(const frag*)&Ks[kt * 16 + lm][(s * 4 + lg) ^ (lm & 7)][0];
        st[kt] = __builtin_amdgcn_mfma_f32_16x16x32_bf16(kf, qf[s], st[kt], 0, 0, 0);
      }
    }
    __builtin_amdgcn_s_setprio(0);

    // ---- softmax (base-2); lane's q = w*16+lm; k = kt*16 + lg*4 + i ----
    const float qg = (float)(q0 + w * 16 + lm);
    float sv[4][4], tmax = -3.0e38f;
    #pragma unroll
    for (int kt = 0; kt < 4; kt++)
      #pragma unroll
      for (int i = 0; i < 4; i++) {
        const float kg = (float)(k0 + kt * 16 + lg * 4 + i);
        const float v = st[kt][i] * sc1 + sl2 * fmaxf(qg - kg, 0.0f);
        sv[kt][i] = v; tmax = fmaxf(tmax, v);
      }
    tmax = fmaxf(tmax, __shfl_xor(tmax, 16, 64));
    tmax = fmaxf(tmax, __shfl_xor(tmax, 32, 64));
    if (__any(tmax > m_i)) {           // exact skip: otherwise alpha == 1
      const float mnew = fmaxf(m_i, tmax);
      const float alpha = exp2f(m_i - mnew);
      m_i = mnew;
      l_i *= alpha;
      float aO[4];
      #pragma unroll
      for (int i = 0; i < 4; i++) aO[i] = __shfl(alpha, lg * 4 + i, 64);
      #pragma unroll
      for (int dt = 0; dt < 4; dt++)
        #pragma unroll
        for (int i = 0; i < 4; i++) acc_o[dt][i] *= aO[i];
    }
    float rsum = 0.f;
    const int qrow = w * 16 + lm;
    #pragma unroll
    for (int kt = 0; kt < 4; kt++) {
      const float p0 = exp2f(sv[kt][0] - m_i), p1 = exp2f(sv[kt][1] - m_i);
      const float p2 = exp2f(sv[kt][2] - m_i), p3 = exp2f(sv[kt][3] - m_i);
      rsum += (p0 + p1) + (p2 + p3);
      ushort4 pk4;
      pk4.x = f2b(p0); pk4.y = f2b(p1); pk4.z = f2b(p2); pk4.w = f2b(p3);
      *(ushort4*)&Ps[qrow][kt * 16 + lg * 4] = pk4;   // 4 consecutive k
    }
    rsum += __shfl_xor(rsum, 16, 64);
    rsum += __shfl_xor(rsum, 32, 64);
    l_i += rsum;

    // ---- O += P V (Ps rows wave-private; same-wave DS order suffices) ----
    __builtin_amdgcn_s_setprio(1);
    #pragma unroll
    for (int c = 0; c < 2; c++) {
      frag ap = *(const frag*)&Ps[w * 16 + lm][c * 32 + lg * 8];
      #pragma unroll
      for (int dt = 0; dt < 4; dt++) {
        frag bv = *(const frag*)&Vt[dt * 16 + lm][(c * 4 + lg) ^ (lm & 7)][0];
        acc_o[dt] = __builtin_amdgcn_mfma_f32_16x16x32_bf16(ap, bv, acc_o[dt], 0, 0, 0);
      }
    }
    __builtin_amdgcn_s_setprio(0);
  }

  // ---- epilogue: normalize, bounce through Ps, coalesced store ----
  float lO[4];
  #pragma unroll
  for (int i = 0; i < 4; i++) lO[i] = 1.0f / __shfl(l_i, lg * 4 + i, 64);
  #pragma unroll
  for (int dt = 0; dt < 4; dt++)
    #pragma unroll
    for (int i = 0; i < 4; i++)
      Ps[w * 16 + lg * 4 + i][dt * 16 + lm] = f2b(acc_o[dt][i] * lO[i]);
  __syncthreads();
  #pragma unroll
  for (int j = 0; j < 2; j++) {
    const int chunk = (w * 2 + j) * 64 + l;
    const int r = chunk >> 3, g = chunk & 7;
    alignas(16) unsigned short tmp[8];
    #pragma unroll
    for (int t = 0; t < 8; t++) tmp[t] = Ps[r][g * 8 + t];
    *(uint4*)(O + (rowbase + q0 + r) * Dc + dbase + g * 8) = *(uint4*)tmp;
  }
}

// ---------- fused: mem1 = RES + ln(X;n1) -> fp32; hln = ln(mem1;cln) -> bf16 ----
__global__ __launch_bounds__(256)
void ln_res_cln_kernel(const float* __restrict__ X, const float* __restrict__ RES,
                       const float* __restrict__ g1, const float* __restrict__ b1,
                       const float* __restrict__ g2, const float* __restrict__ b2,
                       float* __restrict__ OUT1, unsigned short* __restrict__ OUT2)
{
  __shared__ float red4[4];
  const int row = blockIdx.x, tid = threadIdx.x;
  const size_t base = (size_t)row * Dc + tid * 4;
  const float4 xv = *(const float4*)(X + base);
  float s = xv.x + xv.y + xv.z + xv.w;
  s = block_sum(s, red4);
  const float mean = s * (1.0f / Dc);
  const float d0 = xv.x-mean, d1 = xv.y-mean, d2 = xv.z-mean, d3 = xv.w-mean;
  float ss = d0*d0 + d1*d1 + d2*d2 + d3*d3;
  ss = block_sum(ss, red4);
  const float rstd = rsqrtf(ss * (1.0f / Dc) + 1e-5f);
  const int c = tid * 4;
  const float4 rv = *(const float4*)(RES + base);
  float y0 = rv.x + d0*rstd*ldf(g1+c+0) + ldf(b1+c+0);
  float y1 = rv.y + d1*rstd*ldf(g1+c+1) + ldf(b1+c+1);
  float y2 = rv.z + d2*rstd*ldf(g1+c+2) + ldf(b1+c+2);
  float y3 = rv.w + d3*rstd*ldf(g1+c+3) + ldf(b1+c+3);
  *(float4*)(OUT1 + base) = make_float4(y0, y1, y2, y3);
  float s2 = y0 + y1 + y2 + y3;
  s2 = block_sum(s2, red4);
  const float mean2 = s2 * (1.0f / Dc);
  const float e0 = y0-mean2, e1 = y1-mean2, e2 = y2-mean2, e3 = y3-mean2;
  float ss2 = e0*e0 + e1*e1 + e2*e2 + e3*e3;
  ss2 = block_sum(ss2, red4);
  const float rstd2 = rsqrtf(ss2 * (1.0f / Dc) + 1e-5f);
  ushort4 o;
  o.x = f2b(e0*rstd2*ldf(g2+c+0) + ldf(b2+c+0));
  o.y = f2b(e1*rstd2*ldf(g2+c+1) + ldf(b2+c+1));
  o.z = f2b(e2*rstd2*ldf(g2+c+2) + ldf(b2+c+2));
  o.w = f2b(e3*rstd2*ldf(g2+c+3) + ldf(b2+c+3));
  *(ushort4*)(OUT2 + base) = o;
}

__global__ __launch_bounds__(256)   // OUT = ln(X + Y)
void ln_sum_kernel(const float* __restrict__ X, const float* __restrict__ Y,
                   const float* __restrict__ g, const float* __restrict__ be,
                   float* __restrict__ OUT)
{
  __shared__ float red4[4];
  const int row = blockIdx.x, tid = threadIdx.x;
  const size_t base = (size_t)row * Dc + tid * 4;
  const float4 xv = *(const float4*)(X + base);
  const float4 yv = *(const float4*)(Y + base);
  const float x0 = xv.x+yv.x, x1 = xv.y+yv.y, x2 = xv.z+yv.z, x3 = xv.w+yv.w;
  float s = x0 + x1 + x2 + x3;
  s = block_sum(s, red4);
  const float mean = s * (1.0f / Dc);
  const float d0 = x0-mean, d1 = x1-mean, d2 = x2-mean, d3 = x3-mean;
  float ss = d0*d0 + d1*d1 + d2*d2 + d3*d3;
  ss = block_sum(ss, red4);
  const float rstd = rsqrtf(ss * (1.0f / Dc) + 1e-5f);
  const int c = tid * 4;
  float4 o;
  o.x = d0*rstd*ldf(g+c+0) + ldf(be+c+0);
  o.y = d1*rstd*ldf(g+c+1) + ldf(be+c+1);
  o.z = d2*rstd*ldf(g+c+2) + ldf(be+c+2);
  o.w = d3*rstd*ldf(g+c+3) + ldf(be+c+3);
  *(float4*)(OUT + base) = o;
}

// ---------- GLU ----------
__global__ __launch_bounds__(256)
void glu_kernel(const float* __restrict__ H1, float* __restrict__ HG)
{
  const int gid = blockIdx.x * 256 + threadIdx.x;
  const int t = gid >> 8;
  const int c4 = (gid & 255) * 4;
  const float* p = H1 + (size_t)t * (2 * Dc);
  const float4 a = *(const float4*)(p + c4);
  const float4 gg = *(const float4*)(p + Dc + c4);
  float4 o;
  o.x = a.x / (1.0f + expf(-gg.x));
  o.y = a.y / (1.0f + expf(-gg.y));
  o.z = a.z / (1.0f + expf(-gg.z));
  o.w = a.w / (1.0f + expf(-gg.w));
  *(float4*)(HG + (size_t)t * Dc + c4) = o;
}

// ---------- depthwise conv K=5 (+bias, bn-scale, hardswish), bf16 out ----------
__global__ __launch_bounds__(256)
void dwconv_bf16_kernel(const float* __restrict__ HG, const float* __restrict__ w,
                        const float* __restrict__ wb, const float* __restrict__ gn,
                        const float* __restrict__ bb, unsigned short* __restrict__ OUT)
{
  const int gid = blockIdx.x * 256 + threadIdx.x;
  const int d = gid & (Dc - 1);
  const int l = (gid >> 10) & (Lc - 1);
  const int b = gid >> 21;
  const size_t rowb = (size_t)b * Lc;
  float acc = ldf(wb + d);
  #pragma unroll
  for (int s = 0; s < 5; s++) {
    const int lp = l + 2 - s;
    if (lp >= 0 && lp < Lc)
      acc += ldf(w + d * 5 + s) * HG[((rowb + lp) << 10) + d];
  }
  const float rs = rsqrtf(1.0f + 1e-5f);
  const float t = acc * rs * ldf(gn + d) + ldf(bb + d);
  OUT[gid] = f2b(t * fminf(fmaxf(t + 3.0f, 0.0f), 6.0f) * (1.0f / 6.0f));
}

// =====================================================================
extern "C" void kernel_launch(void* const* d_in, const int* in_sizes, int n_in,
                              void* d_out, int out_size, void* d_ws, size_t ws_size,
                              hipStream_t stream) {
  (void)in_sizes; (void)n_in; (void)out_size; (void)ws_size;
  const float* mem    = (const float*)d_in[0];
  const float* wq     = (const float*)d_in[1];
  const float* bq     = (const float*)d_in[2];
  const float* wk     = (const float*)d_in[3];
  const float* bk     = (const float*)d_in[4];
  const float* wv     = (const float*)d_in[5];
  const float* bv     = (const float*)d_in[6];
  const float* wo     = (const float*)d_in[7];
  const float* bo     = (const float*)d_in[8];
  const float* n1g    = (const float*)d_in[9];
  const float* n1b    = (const float*)d_in[10];
  const float* clng   = (const float*)d_in[11];
  const float* clnb   = (const float*)d_in[12];
  const float* pw1w   = (const float*)d_in[13];
  const float* pw1b   = (const float*)d_in[14];
  const float* dww    = (const float*)d_in[15];
  const float* dwb    = (const float*)d_in[16];
  const float* bng    = (const float*)d_in[17];
  const float* bnb    = (const float*)d_in[18];
  const float* pw2w   = (const float*)d_in[19];
  const float* pw2b   = (const float*)d_in[20];
  const float* projw  = (const float*)d_in[21];
  const float* projb  = (const float*)d_in[22];
  const float* proj2w = (const float*)d_in[23];
  const float* proj2b = (const float*)d_in[24];
  const float* lin1w  = (const float*)d_in[25];
  const float* lin1b  = (const float*)d_in[26];
  const float* lin2w  = (const float*)d_in[27];
  const float* lin2b  = (const float*)d_in[28];
  const float* n3g    = (const float*)d_in[29];
  const float* n3b    = (const float*)d_in[30];
  float* out = (float*)d_out;

  char* base = (char*)d_ws;
  float* qb   = (float*)base;          // q fp32 -> tgt2 fp32
  float* kb   = qb + TD;               // k fp32 -> mem1
  float* big1 = kb + TD;               // h1 lo -> mem2 fp32
  float* big2 = big1 + TD;             // h1 hi -> conv_out
  float* ob   = big2 + TD;             // hg -> ffout
  unsigned short* abf  = (unsigned short*)(base + 5 * TD * 4);  // bf16 hub
  unsigned short* qbf  = abf + TD;     // rope-q -> mem2 bf16
  unsigned short* kbf  = qbf + TD;
  unsigned short* vtb  = kbf + TD;     // V^T bf16  [b][1024 d][2048 l]
  unsigned short* m1T  = vtb + TD;
  unsigned short* ffbbf= m1T + TD;     // NT*FF = 4*TD shorts
  unsigned short* wt   = ffbbf + 4 * TD;
  unsigned short* wqT    = wt;            // [1024][1024] } contiguous => [3072][1024] fused QKV B^T
  unsigned short* wkT    = wqT + MEG;
  unsigned short* wvT    = wkT + MEG;
  unsigned short* woT    = wvT + MEG;
  unsigned short* pw1T   = woT + MEG;     // [2048][1024]
  unsigned short* pw2T   = pw1T + 2*MEG;  // [1024][1024]
  unsigned short* proj2T = pw2T + MEG;    // [1024][1024]
  unsigned short* projwT = proj2T + MEG;  // [2048][2048]
  unsigned short* lin1T  = projwT + 4*MEG;// [4096][1024]
  unsigned short* lin2T  = lin1T + 4*MEG; // [1024][4096]
  float* pet = (float*)(lin2T + 4*MEG);   // [2048][64] rope table

  const dim3 blk(256);
  const long long LD = (long long)Lc * Dc;

  // ---- fused weight transposes + rope table ----
  TPack tp;
  const float* tin[10]  = {wq, wk, wv, wo, pw1w, pw2w, proj2w, projw, lin1w, lin2w};
  unsigned short* tout[10] = {wqT, wkT, wvT, woT, pw1T, pw2T, proj2T, projwT, lin1T, lin2T};
  const int tR[10] = {1024,1024,1024,1024,1024,1024,1024,2048,1024,4096};
  const int tC[10] = {1024,1024,1024,1024,2048,1024,1024,2048,4096,1024};
  int startAcc = 0;
  for (int i = 0; i < 10; i++) {
    tp.in[i] = tin[i]; tp.out[i] = tout[i];
    tp.R[i] = tR[i]; tp.C[i] = tC[i]; tp.tx[i] = tC[i] / 64;
    tp.start[i] = startAcc;
    startAcc += (tR[i] / 64) * (tC[i] / 64);
  }
  fused_transpose_kernel<<<dim3(startAcc), blk, 0, stream>>>(tp);
  pe_fill_kernel<<<dim3(Lc * 64 / 256), blk, 0, stream>>>(pet);

  // ---- attention ----
  convert_bf16_kernel<<<dim3((unsigned)(TD/1024)),blk,0,stream>>>(mem, abf);
  // fused QKV: N=3072, q->qb fp32, k->kb fp32, V->vtb transposed bf16 directly
  mfma_gemm_kernel<128,EPI_QKV,false,false><<<dim3(24,32,1),blk,0,stream>>>(
      abf, wqT, bq, bk, bv, nullptr, qb, vtb, NT, 3*Dc, Dc, 0, 0, 0);
  rope2_kernel<<<dim3(2*NT*Hc/256),blk,0,stream>>>(qb, kb, pet, qbf, kbf);
  flash_attn_mfma_kernel<<<dim3(Lc/64, Bc*Hc),blk,0,stream>>>(qbf,kbf,vtb,abf);
  mfma_gemm_kernel<64,EPI_BIAS,false,false><<<dim3(8,64,1),blk,0,stream>>>(
      abf,woT,bo,nullptr,nullptr,nullptr,qb,nullptr,NT,Dc,Dc,0,0,0);
  // mem1 (fp32 -> kb) and ln(mem1) (bf16 -> abf) in one pass
  ln_res_cln_kernel<<<dim3(NT),blk,0,stream>>>(qb, mem, n1g, n1b, clng, clnb, kb, abf);

  // ---- conv block ----
  mfma_gemm_kernel<128,EPI_BIAS,false,false><<<dim3(16,32,1),blk,0,stream>>>(
      abf,pw1T,pw1b,nullptr,nullptr,nullptr,big1,nullptr,NT,2*Dc,Dc,0,0,0);
  glu_kernel<<<dim3((unsigned)(TD/4/256)),blk,0,stream>>>(big1, ob);
  dwconv_bf16_kernel<<<dim3((unsigned)(TD/256)),blk,0,stream>>>(ob, dww, dwb, bng, bnb, abf);
  mfma_gemm_kernel<64,EPI_ADDROW0,false,false><<<dim3(8,64,1),blk,0,stream>>>(
      abf,pw2T,pw2b,nullptr,nullptr,kb,big2,nullptr,NT,Dc,Dc,0,0,0);

  // ---- proj path ----
  transpose_convert_kernel<<<dim3(16,32,2),blk,0,stream>>>(kb, m1T, 2048, 1024, LD, LD);
  mfma_gemm_kernel<64,EPI_BIAS_ROW,true,false><<<dim3(8,32,2),blk,0,stream>>>(
      projwT,m1T,projb,nullptr,nullptr,nullptr,nullptr,abf,Lc,Dc,Lc,0,LD,LD);
  // mem2 = proj@proj2 + conv_out: fp32 -> big1 AND bf16 -> qbf (feeds lin1)
  mfma_gemm_kernel<64,EPI_ADD,false,true><<<dim3(8,64,1),blk,0,stream>>>(
      abf,proj2T,proj2b,nullptr,nullptr,big2,big1,qbf,NT,Dc,Dc,0,0,0);

  // ---- feed-forward ----
  mfma_gemm_kernel<128,EPI_GELU,true,false><<<dim3(32,32,1),blk,0,stream>>>(
      qbf,lin1T,lin1b,nullptr,nullptr,nullptr,nullptr,ffbbf,NT,FFc,Dc,0,0,0);
  mfma_gemm_kernel<64,EPI_BIAS,false,false><<<dim3(8,64,1),blk,0,stream>>>(
      ffbbf,lin2T,lin2b,nullptr,nullptr,nullptr,ob,nullptr,NT,Dc,FFc,0,0,0);

  // ---- final: out = ln(mem2 + ffout) ----
  ln_sum_kernel<<<dim3(NT),blk,0,stream>>>(big1, ob, n3g, n3b, out);
}

// Round 3
// 649.716 us; speedup vs baseline: 1.1182x; 1.0791x over previous
//
#include <hip/hip_runtime.h>
#include <hip/hip_bf16.h>
#include <math.h>

constexpr int Bc = 2, Lc = 2048, Dc = 1024, Hc = 16, HDc = 64, FFc = 4096;
constexpr int NT = Bc * Lc;              // 4096 tokens
constexpr size_t TD = (size_t)NT * Dc;   // 4194304 elements per [B,L,D] tensor
constexpr size_t MEG = 1024 * 1024;

__device__ __forceinline__ float ldf(const float* p) { return *p; }
__device__ __forceinline__ unsigned short f2b(float f) {
  __hip_bfloat16 h = __float2bfloat16(f);
  return *reinterpret_cast<unsigned short*>(&h);
}

using frag   = __attribute__((ext_vector_type(8))) short;   // 8 bf16 (4 VGPRs)
using f32x4v = __attribute__((ext_vector_type(4))) float;   // MFMA C/D

// async global -> LDS, 16B per lane; LDS dest = wave-uniform base + lane*16
__device__ __forceinline__ void async16(const unsigned short* g, unsigned short* l) {
  __builtin_amdgcn_global_load_lds(
      (const __attribute__((address_space(1))) unsigned int*)g,
      (__attribute__((address_space(3))) unsigned int*)l, 16, 0, 0);
}

// ---------- block reductions (blockDim.x == 256 = 4 waves) ----------
__device__ __forceinline__ float block_sum(float v, float* red) {
  const int lane = threadIdx.x & 63, w = threadIdx.x >> 6;
  #pragma unroll
  for (int o = 32; o > 0; o >>= 1) v += __shfl_down(v, o, 64);
  __syncthreads();
  if (lane == 0) red[w] = v;
  __syncthreads();
  return red[0] + red[1] + red[2] + red[3];
}

// ---------- fp32 -> bf16 convert ----------
__global__ __launch_bounds__(256)
void convert_bf16_kernel(const float* __restrict__ IN, unsigned short* __restrict__ OUT)
{
  const size_t gid = (size_t)blockIdx.x * 256 + threadIdx.x;
  const float4 v = *(const float4*)(IN + gid * 4);
  ushort4 o;
  o.x = f2b(v.x); o.y = f2b(v.y); o.z = f2b(v.z); o.w = f2b(v.w);
  *(ushort4*)(OUT + gid * 4) = o;
}

// ---------- fp32 [R,C] -> bf16 [C,R] transpose-convert (z-batched) ----------
__global__ __launch_bounds__(256)
void transpose_convert_kernel(const float* __restrict__ IN, unsigned short* __restrict__ OUT,
                              int R, int C, long long sIn, long long sOut)
{
  __shared__ float tile[64][65];
  const int t = threadIdx.x;
  const float* in = IN + (long long)blockIdx.z * sIn;
  unsigned short* out = OUT + (long long)blockIdx.z * sOut;
  const int r0 = blockIdx.y * 64, c0 = blockIdx.x * 64;
  #pragma unroll
  for (int i = 0; i < 4; i++) {
    const int r = (t >> 4) + i * 16, c4 = (t & 15) * 4;
    const float4 v = *(const float4*)(in + (size_t)(r0 + r) * C + c0 + c4);
    tile[r][c4+0] = v.x; tile[r][c4+1] = v.y; tile[r][c4+2] = v.z; tile[r][c4+3] = v.w;
  }
  __syncthreads();
  #pragma unroll
  for (int i = 0; i < 4; i++) {
    const int cc = (t >> 4) + i * 16, rr4 = (t & 15) * 4;
    ushort4 o;
    o.x = f2b(tile[rr4+0][cc]); o.y = f2b(tile[rr4+1][cc]);
    o.z = f2b(tile[rr4+2][cc]); o.w = f2b(tile[rr4+3][cc]);
    *(ushort4*)(out + (size_t)(c0 + cc) * R + r0 + rr4) = o;
  }
}

// ---------- fused weight transposes: 10 segments in one launch ----------
struct TPack {
  const float* in[10]; unsigned short* out[10];
  int R[10], C[10], tx[10], start[10];
};
__global__ __launch_bounds__(256)
void fused_transpose_kernel(TPack p)
{
  __shared__ float tile[64][65];
  const int bid = blockIdx.x;
  int s = 0;
  #pragma unroll
  for (int i = 1; i < 10; i++) s = (bid >= p.start[i]) ? i : s;
  const float* in = p.in[s];
  unsigned short* out = p.out[s];
  const int R = p.R[s], C = p.C[s];
  const int local = bid - p.start[s];
  const int bx = local % p.tx[s], by = local / p.tx[s];
  const int r0 = by * 64, c0 = bx * 64;
  const int t = threadIdx.x;
  #pragma unroll
  for (int i = 0; i < 4; i++) {
    const int r = (t >> 4) + i * 16, c4 = (t & 15) * 4;
    const float4 v = *(const float4*)(in + (size_t)(r0 + r) * C + c0 + c4);
    tile[r][c4+0] = v.x; tile[r][c4+1] = v.y; tile[r][c4+2] = v.z; tile[r][c4+3] = v.w;
  }
  __syncthreads();
  #pragma unroll
  for (int i = 0; i < 4; i++) {
    const int cc = (t >> 4) + i * 16, rr4 = (t & 15) * 4;
    ushort4 o;
    o.x = f2b(tile[rr4+0][cc]); o.y = f2b(tile[rr4+1][cc]);
    o.z = f2b(tile[rr4+2][cc]); o.w = f2b(tile[rr4+3][cc]);
    *(ushort4*)(out + (size_t)(c0 + cc) * R + r0 + rr4) = o;
  }
}

// ---------- MFMA bf16 GEMM, double-buffered global_load_lds staging ----------
// C[m,n] = sum_k A[m,k] * Bt[n,k]. Tile BM x 128, BK=32, 2-phase pipeline:
//   stage(t+1 -> buf^1) issued BEFORE compute(t on buf); ONE barrier per iter,
//   so the vmcnt drain lands after the MFMA cluster instead of before it.
// Swizzle sigma(r) = (r>>1)&3 (both staged-source granule and ds_read granule):
//   bank start = 16*(r&1) + 4*(c^sigma) -> distinct across 8 rows, 2-way over
//   16 (free), vs the old (r&3) which was a 4-way conflict.
constexpr int EPI_BIAS = 0, EPI_BIAS_ROW = 1, EPI_GELU = 2, EPI_ADD = 3, EPI_ADDROW0 = 4,
              EPI_QKV = 5;

template<int BM, int EPI, bool OUTBF, bool OUTBOTH>
__global__ __launch_bounds__(256)
void mfma_gemm_kernel(const unsigned short* __restrict__ A, const unsigned short* __restrict__ Bt,
                      const float* __restrict__ bias, const float* __restrict__ bias2,
                      const float* __restrict__ bias3, const float* __restrict__ extra,
                      float* __restrict__ C, unsigned short* __restrict__ Cbf,
                      int M, int N, int K,
                      long long sA, long long sB, long long sC)
{
  constexpr int NTt = (BM == 128) ? 4 : 2;   // 16-wide n-fragments per wave
  __shared__ unsigned short As[2][BM][4][8];
  __shared__ unsigned short Bs[2][128][4][8];
  const int tid = threadIdx.x;
  const int l = tid & 63, w = tid >> 6;
  const int wm = (BM == 128) ? (w & 1) * 64 : 0;
  const int wn = (BM == 128) ? (w >> 1) * 64 : w * 32;
  const int m0 = blockIdx.y * BM, n0 = blockIdx.x * 128;
  const unsigned short* Ap = A + (long long)blockIdx.z * sA;
  const unsigned short* Bp = Bt + (long long)blockIdx.z * sB;

  f32x4v acc[4][NTt];
  #pragma unroll
  for (int mt = 0; mt < 4; mt++)
    #pragma unroll
    for (int nt = 0; nt < NTt; nt++) acc[mt][nt] = {0.f, 0.f, 0.f, 0.f};

  const int c_ = l >> 4, rm = l & 15;
  int rrB[2], ggB[2];
  #pragma unroll
  for (int j = 0; j < 2; j++) {
    const int chunk = w * 128 + j * 64 + l;
    rrB[j] = chunk >> 2;
    ggB[j] = (chunk & 3) ^ ((rrB[j] >> 1) & 3);
  }
  int rrA = 0, ggA = 0;
  if constexpr (BM == 64) {
    const int chunkA = w * 64 + l;
    rrA = chunkA >> 2;
    ggA = (chunkA & 3) ^ ((rrA >> 1) & 3);
  }

  auto stage = [&](int bi, int k0) {
    if constexpr (BM == 128) {
      #pragma unroll
      for (int j = 0; j < 2; j++) {
        async16(Ap + (size_t)(m0 + rrB[j]) * K + k0 + ggB[j] * 8,
                &As[bi][0][0][0] + (size_t)(w * 128 + j * 64) * 8);
        async16(Bp + (size_t)(n0 + rrB[j]) * K + k0 + ggB[j] * 8,
                &Bs[bi][0][0][0] + (size_t)(w * 128 + j * 64) * 8);
      }
    } else {
      async16(Ap + (size_t)(m0 + rrA) * K + k0 + ggA * 8,
              &As[bi][0][0][0] + (size_t)(w * 64) * 8);
      #pragma unroll
      for (int j = 0; j < 2; j++)
        async16(Bp + (size_t)(n0 + rrB[j]) * K + k0 + ggB[j] * 8,
                &Bs[bi][0][0][0] + (size_t)(w * 128 + j * 64) * 8);
    }
  };

  stage(0, 0);
  __syncthreads();          // vmcnt(0) drain + barrier
  int cur = 0;
  const int sg = (rm >> 1) & 3;

  for (int k0 = 0; k0 < K; k0 += 32) {
    if (k0 + 32 < K) stage(cur ^ 1, k0 + 32);   // prefetch next tile (other buffer)

    frag af[4], bfr[NTt];
    #pragma unroll
    for (int mt = 0; mt < 4; mt++)
      af[mt] = *(const frag*)&As[cur][wm + mt * 16 + rm][c_ ^ sg][0];
    #pragma unroll
    for (int nt = 0; nt < NTt; nt++)
      bfr[nt] = *(const frag*)&Bs[cur][wn + nt * 16 + rm][c_ ^ sg][0];
    #pragma unroll
    for (int mt = 0; mt < 4; mt++)
      #pragma unroll
      for (int nt = 0; nt < NTt; nt++)
        acc[mt][nt] = __builtin_amdgcn_mfma_f32_16x16x32_bf16(af[mt], bfr[nt], acc[mt][nt], 0, 0, 0);

    __syncthreads();        // drains this iter's lgkm reads + next-tile vmcnt
    cur ^= 1;
  }

  float* Cp = C + (long long)blockIdx.z * sC;
  unsigned short* Cbp = Cbf + (long long)blockIdx.z * sC;
  #pragma unroll
  for (int mt = 0; mt < 4; mt++) {
    #pragma unroll
    for (int nt = 0; nt < NTt; nt++) {
      const int mq = m0 + wm + mt * 16 + c_ * 4;   // quad-base row (i = 0..3 below)
      const int n  = n0 + wn + nt * 16 + rm;       // C/D: col=lane&15
      if constexpr (EPI == EPI_QKV) {
        // n in [0,1024): q (fp32) | [1024,2048): k (fp32) | [2048,3072): V^T bf16
        const float* bp = (n < 1024) ? bias : ((n < 2048) ? bias2 : bias3);
        const float bv_ = ldf(bp + (n & 1023));
        const float r0 = acc[mt][nt][0] + bv_;
        const float r1 = acc[mt][nt][1] + bv_;
        const float r2 = acc[mt][nt][2] + bv_;
        const float r3 = acc[mt][nt][3] + bv_;
        if (n < 2048) {
          float* dst = Cp + (size_t)(n >> 10) * TD + (size_t)mq * Dc + (n & 1023);
          dst[0] = r0; dst[Dc] = r1; dst[2 * Dc] = r2; dst[3 * Dc] = r3;
        } else {
          ushort4 o;
          o.x = f2b(r0); o.y = f2b(r1); o.z = f2b(r2); o.w = f2b(r3);
          *(ushort4*)(Cbp + (size_t)(mq >> 11) * ((size_t)Lc * Dc)
                      + (size_t)(n - 2048) * Lc + (mq & (Lc - 1))) = o;
        }
      } else {
        #pragma unroll
        for (int i = 0; i < 4; i++) {
          const int m = mq + i;                     // C/D: row=(lane>>4)*4+reg
          float r = acc[mt][nt][i];
          if constexpr (EPI == EPI_BIAS || EPI == EPI_GELU || EPI == EPI_ADD || EPI == EPI_ADDROW0)
            r += ldf(bias + n);
          if constexpr (EPI == EPI_BIAS_ROW) r += ldf(bias + m);
          if constexpr (EPI == EPI_GELU)
            r = 0.5f * r * (1.0f + erff(r * 0.70710678118654752f));
          if constexpr (EPI == EPI_ADD) r += extra[(size_t)m * N + n];
          if constexpr (EPI == EPI_ADDROW0) r += extra[(size_t)(m >> 11) * ((size_t)Lc * Dc) + n];
          if constexpr (OUTBOTH) { Cp[(size_t)m * N + n] = r; Cbp[(size_t)m * N + n] = f2b(r); }
          else if constexpr (OUTBF) Cbp[(size_t)m * N + n] = f2b(r);
          else                      Cp[(size_t)m * N + n] = r;
        }
      }
    }
  }
}

// ---------- RoPE table fill ----------
__global__ __launch_bounds__(256)
void pe_fill_kernel(float* __restrict__ pet)
{
  const int gid = blockIdx.x * 256 + threadIdx.x;  // Lc*64
  const int l = gid >> 6, t = gid & 63;
  const int j = t & 31;
  const float wj = exp2f(-(float)j * (13.2877123795494f / 32.0f));
  const float ang = (float)l * wj;
  pet[gid] = (t < 32) ? cosf(ang) : sinf(ang);
}

// ---------- fused RoPE for Q and K: fp32 in, bf16 out ----------
__global__ __launch_bounds__(256)
void rope2_kernel(const float* __restrict__ Qi, const float* __restrict__ Ki,
                  const float* __restrict__ pet,
                  unsigned short* __restrict__ Qo, unsigned short* __restrict__ Ko)
{
  int gid = blockIdx.x * 256 + threadIdx.x;  // 2*NT*Hc
  const int sel = gid >= NT * Hc;
  if (sel) gid -= NT * Hc;
  const float* X = sel ? Ki : Qi;
  unsigned short* O = sel ? Ko : Qo;
  const int h = gid & (Hc - 1);
  const int token = gid >> 4;
  const int l = token & (Lc - 1);
  const float* p = X + (size_t)token * Dc + h * HDc;
  unsigned short* po = O + (size_t)token * Dc + h * HDc;
  const float* pr = pet + l * 64;
  float x[64], out[64];
  #pragma unroll
  for (int i = 0; i < 16; i++) *(float4*)&x[4*i] = *(const float4*)&p[4*i];
  #pragma unroll
  for (int u = 0; u < 32; u++) {
    const int base = (u < 16) ? (2 * u) : (32 + 2 * (u - 16));
    const float c = pr[base], s = pr[base + 1];
    out[u]      = x[2*u] * c - x[2*u+1] * s;
    out[32 + u] = x[2*u] * s + x[2*u+1] * c;
  }
  #pragma unroll
  for (int i = 0; i < 16; i++) {
    ushort4 o;
    o.x = f2b(out[4*i+0]); o.y = f2b(out[4*i+1]);
    o.z = f2b(out[4*i+2]); o.w = f2b(out[4*i+3]);
    *(ushort4*)&po[4*i] = o;
  }
}

// ---------- MFMA flash attention v4 ----------
// One block = 64 q-rows x one (b,h); grid 32x32 = 1024 blocks -> 4 blocks/CU.
// 4 waves x 16 q-rows. S^T = K*Q^T; softmax at fixed lane (2-shfl reduce);
// exact rescale-skip when no row max grew (alpha==1 -> identity).
__global__ __launch_bounds__(256)
void flash_attn_mfma_kernel(const unsigned short* __restrict__ Q,
                            const unsigned short* __restrict__ K,
                            const unsigned short* __restrict__ VT,
                            unsigned short* __restrict__ O)
{
  __shared__ unsigned short Qs[64][8][8];
  __shared__ unsigned short Ks[64][8][8];
  __shared__ unsigned short Vt[64][8][8];
  __shared__ unsigned short Ps[64][72];
  const int tid = threadIdx.x;
  const int l = tid & 63, w = tid >> 6;
  const int lg = l >> 4, lm = l & 15;
  const int q0 = blockIdx.x * 64;
  const int bh = blockIdx.y;
  const int b = bh >> 4, h = bh & 15;
  const size_t rowbase = (size_t)b * Lc;
  const size_t vbase = (size_t)b * Lc * Dc;
  const int dbase = h * 64;
  const float sc1 = 0.125f * 1.44269504f;                  // scale * log2(e)
  const float sl2 = exp2f(-0.5f * (float)h) * 1.44269504f; // slope * log2(e)

  // ---- stage Q (64 rows x 64 d = 512 chunks) ----
  #pragma unroll
  for (int j = 0; j < 2; j++) {
    const int chunk = (w * 2 + j) * 64 + l;
    const int r = chunk >> 3, gsrc = (chunk & 7) ^ (r & 7);
    async16(Q + (rowbase + q0 + r) * Dc + dbase + gsrc * 8,
            &Qs[0][0][0] + (size_t)chunk * 8);
  }
  __syncthreads();
  frag qf[2];
  #pragma unroll
  for (int s = 0; s < 2; s++)
    qf[s] = *(const frag*)&Qs[w * 16 + lm][(s * 4 + lg) ^ (lm & 7)][0];

  float m_i = -3.0e38f, l_i = 0.f;
  f32x4v acc_o[4];
  #pragma unroll
  for (int dt = 0; dt < 4; dt++) acc_o[dt] = {0.f, 0.f, 0.f, 0.f};

  for (int k0 = 0; k0 < Lc; k0 += 64) {
    __syncthreads();   // prior tile reads complete
    #pragma unroll
    for (int j = 0; j < 2; j++) {
      const int chunk = (w * 2 + j) * 64 + l;
      const int r = chunk >> 3, gsrc = (chunk & 7) ^ (r & 7);
      async16(K + (rowbase + k0 + r) * Dc + dbase + gsrc * 8,
              &Ks[0][0][0] + (size_t)chunk * 8);
      async16(VT + vbase + (size_t)(dbase + r) * Lc + k0 + gsrc * 8,
              &Vt[0][0][0] + (size_t)chunk * 8);
    }
    __syncthreads();

    // ---- S^T = K Q^T : rows k (64), cols q (16 of this wave) ----
    f32x4v st[4];
    #pragma unroll
    for (int kt = 0; kt < 4; kt++) st[kt] = {0.f, 0.f, 0.f, 0.f};
    __builtin_amdgcn_s_setprio(1);
    #pragma unroll
    for (int kt = 0; kt < 4; kt++) {
      #pragma unroll
      for (int s = 0; s < 2; s++) {
        frag kf = *(const frag*)&Ks[kt * 16 + lm][(s * 4 + lg) ^ (lm & 7)][0];
        st[kt] = __builtin_amdgcn_mfma_f32_16x16x32_bf16(kf, qf[s], st[kt], 0, 0, 0);
      }
    }
    __builtin_amdgcn_s_setprio(0);

    // ---- softmax (base-2); lane's q = w*16+lm; k = kt*16 + lg*4 + i ----
    const float qg = (float)(q0 + w * 16 + lm);
    float sv[4][4], tmax = -3.0e38f;
    #pragma unroll
    for (int kt = 0; kt < 4; kt++)
      #pragma unroll
      for (int i = 0; i < 4; i++) {
        const float kg = (float)(k0 + kt * 16 + lg * 4 + i);
        const float v = st[kt][i] * sc1 + sl2 * fmaxf(qg - kg, 0.0f);
        sv[kt][i] = v; tmax = fmaxf(tmax, v);
      }
    tmax = fmaxf(tmax, __shfl_xor(tmax, 16, 64));
    tmax = fmaxf(tmax, __shfl_xor(tmax, 32, 64));
    if (__any(tmax > m_i)) {           // exact skip: otherwise alpha == 1
      const float mnew = fmaxf(m_i, tmax);
      const float alpha = exp2f(m_i - mnew);
      m_i = mnew;
      l_i *= alpha;
      float aO[4];
      #pragma unroll
      for (int i = 0; i < 4; i++) aO[i] = __shfl(alpha, lg * 4 + i, 64);
      #pragma unroll
      for (int dt = 0; dt < 4; dt++)
        #pragma unroll
        for (int i = 0; i < 4; i++) acc_o[dt][i] *= aO[i];
    }
    float rsum = 0.f;
    const int qrow = w * 16 + lm;
    #pragma unroll
    for (int kt = 0; kt < 4; kt++) {
      const float p0 = exp2f(sv[kt][0] - m_i), p1 = exp2f(sv[kt][1] - m_i);
      const float p2 = exp2f(sv[kt][2] - m_i), p3 = exp2f(sv[kt][3] - m_i);
      rsum += (p0 + p1) + (p2 + p3);
      ushort4 pk4;
      pk4.x = f2b(p0); pk4.y = f2b(p1); pk4.z = f2b(p2); pk4.w = f2b(p3);
      *(ushort4*)&Ps[qrow][kt * 16 + lg * 4] = pk4;   // 4 consecutive k
    }
    rsum += __shfl_xor(rsum, 16, 64);
    rsum += __shfl_xor(rsum, 32, 64);
    l_i += rsum;

    // ---- O += P V (Ps rows wave-private; same-wave DS order suffices) ----
    __builtin_amdgcn_s_setprio(1);
    #pragma unroll
    for (int c = 0; c < 2; c++) {
      frag ap = *(const frag*)&Ps[w * 16 + lm][c * 32 + lg * 8];
      #pragma unroll
      for (int dt = 0; dt < 4; dt++) {
        frag bv = *(const frag*)&Vt[dt * 16 + lm][(c * 4 + lg) ^ (lm & 7)][0];
        acc_o[dt] = __builtin_amdgcn_mfma_f32_16x16x32_bf16(ap, bv, acc_o[dt], 0, 0, 0);
      }
    }
    __builtin_amdgcn_s_setprio(0);
  }

  // ---- epilogue: normalize, bounce through Ps, coalesced store ----
  float lO[4];
  #pragma unroll
  for (int i = 0; i < 4; i++) lO[i] = 1.0f / __shfl(l_i, lg * 4 + i, 64);
  #pragma unroll
  for (int dt = 0; dt < 4; dt++)
    #pragma unroll
    for (int i = 0; i < 4; i++)
      Ps[w * 16 + lg * 4 + i][dt * 16 + lm] = f2b(acc_o[dt][i] * lO[i]);
  __syncthreads();
  #pragma unroll
  for (int j = 0; j < 2; j++) {
    const int chunk = (w * 2 + j) * 64 + l;
    const int r = chunk >> 3, g = chunk & 7;
    alignas(16) unsigned short tmp[8];
    #pragma unroll
    for (int t = 0; t < 8; t++) tmp[t] = Ps[r][g * 8 + t];
    *(uint4*)(O + (rowbase + q0 + r) * Dc + dbase + g * 8) = *(uint4*)tmp;
  }
}

// ---------- fused: mem1 = RES + ln(X;n1) -> fp32; hln = ln(mem1;cln) -> bf16 ----
__global__ __launch_bounds__(256)
void ln_res_cln_kernel(const float* __restrict__ X, const float* __restrict__ RES,
                       const float* __restrict__ g1, const float* __restrict__ b1,
                       const float* __restrict__ g2, const float* __restrict__ b2,
                       float* __restrict__ OUT1, unsigned short* __restrict__ OUT2)
{
  __shared__ float red4[4];
  const int row = blockIdx.x, tid = threadIdx.x;
  const size_t base = (size_t)row * Dc + tid * 4;
  const float4 xv = *(const float4*)(X + base);
  float s = xv.x + xv.y + xv.z + xv.w;
  s = block_sum(s, red4);
  const float mean = s * (1.0f / Dc);
  const float d0 = xv.x-mean, d1 = xv.y-mean, d2 = xv.z-mean, d3 = xv.w-mean;
  float ss = d0*d0 + d1*d1 + d2*d2 + d3*d3;
  ss = block_sum(ss, red4);
  const float rstd = rsqrtf(ss * (1.0f / Dc) + 1e-5f);
  const int c = tid * 4;
  const float4 rv = *(const float4*)(RES + base);
  float y0 = rv.x + d0*rstd*ldf(g1+c+0) + ldf(b1+c+0);
  float y1 = rv.y + d1*rstd*ldf(g1+c+1) + ldf(b1+c+1);
  float y2 = rv.z + d2*rstd*ldf(g1+c+2) + ldf(b1+c+2);
  float y3 = rv.w + d3*rstd*ldf(g1+c+3) + ldf(b1+c+3);
  *(float4*)(OUT1 + base) = make_float4(y0, y1, y2, y3);
  float s2 = y0 + y1 + y2 + y3;
  s2 = block_sum(s2, red4);
  const float mean2 = s2 * (1.0f / Dc);
  const float e0 = y0-mean2, e1 = y1-mean2, e2 = y2-mean2, e3 = y3-mean2;
  float ss2 = e0*e0 + e1*e1 + e2*e2 + e3*e3;
  ss2 = block_sum(ss2, red4);
  const float rstd2 = rsqrtf(ss2 * (1.0f / Dc) + 1e-5f);
  ushort4 o;
  o.x = f2b(e0*rstd2*ldf(g2+c+0) + ldf(b2+c+0));
  o.y = f2b(e1*rstd2*ldf(g2+c+1) + ldf(b2+c+1));
  o.z = f2b(e2*rstd2*ldf(g2+c+2) + ldf(b2+c+2));
  o.w = f2b(e3*rstd2*ldf(g2+c+3) + ldf(b2+c+3));
  *(ushort4*)(OUT2 + base) = o;
}

__global__ __launch_bounds__(256)   // OUT = ln(X + Y)
void ln_sum_kernel(const float* __restrict__ X, const float* __restrict__ Y,
                   const float* __restrict__ g, const float* __restrict__ be,
                   float* __restrict__ OUT)
{
  __shared__ float red4[4];
  const int row = blockIdx.x, tid = threadIdx.x;
  const size_t base = (size_t)row * Dc + tid * 4;
  const float4 xv = *(const float4*)(X + base);
  const float4 yv = *(const float4*)(Y + base);
  const float x0 = xv.x+yv.x, x1 = xv.y+yv.y, x2 = xv.z+yv.z, x3 = xv.w+yv.w;
  float s = x0 + x1 + x2 + x3;
  s = block_sum(s, red4);
  const float mean = s * (1.0f / Dc);
  const float d0 = x0-mean, d1 = x1-mean, d2 = x2-mean, d3 = x3-mean;
  float ss = d0*d0 + d1*d1 + d2*d2 + d3*d3;
  ss = block_sum(ss, red4);
  const float rstd = rsqrtf(ss * (1.0f / Dc) + 1e-5f);
  const int c = tid * 4;
  float4 o;
  o.x = d0*rstd*ldf(g+c+0) + ldf(be+c+0);
  o.y = d1*rstd*ldf(g+c+1) + ldf(be+c+1);
  o.z = d2*rstd*ldf(g+c+2) + ldf(be+c+2);
  o.w = d3*rstd*ldf(g+c+3) + ldf(be+c+3);
  *(float4*)(OUT + base) = o;
}

// ---------- GLU ----------
__global__ __launch_bounds__(256)
void glu_kernel(const float* __restrict__ H1, float* __restrict__ HG)
{
  const int gid = blockIdx.x * 256 + threadIdx.x;
  const int t = gid >> 8;
  const int c4 = (gid & 255) * 4;
  const float* p = H1 + (size_t)t * (2 * Dc);
  const float4 a = *(const float4*)(p + c4);
  const float4 gg = *(const float4*)(p + Dc + c4);
  float4 o;
  o.x = a.x / (1.0f + expf(-gg.x));
  o.y = a.y / (1.0f + expf(-gg.y));
  o.z = a.z / (1.0f + expf(-gg.z));
  o.w = a.w / (1.0f + expf(-gg.w));
  *(float4*)(HG + (size_t)t * Dc + c4) = o;
}

// ---------- depthwise conv K=5 (+bias, bn-scale, hardswish), bf16 out ----------
__global__ __launch_bounds__(256)
void dwconv_bf16_kernel(const float* __restrict__ HG, const float* __restrict__ w,
                        const float* __restrict__ wb, const float* __restrict__ gn,
                        const float* __restrict__ bb, unsigned short* __restrict__ OUT)
{
  const int gid = blockIdx.x * 256 + threadIdx.x;
  const int d = gid & (Dc - 1);
  const int l = (gid >> 10) & (Lc - 1);
  const int b = gid >> 21;
  const size_t rowb = (size_t)b * Lc;
  float acc = ldf(wb + d);
  #pragma unroll
  for (int s = 0; s < 5; s++) {
    const int lp = l + 2 - s;
    if (lp >= 0 && lp < Lc)
      acc += ldf(w + d * 5 + s) * HG[((rowb + lp) << 10) + d];
  }
  const float rs = rsqrtf(1.0f + 1e-5f);
  const float t = acc * rs * ldf(gn + d) + ldf(bb + d);
  OUT[gid] = f2b(t * fminf(fmaxf(t + 3.0f, 0.0f), 6.0f) * (1.0f / 6.0f));
}

// =====================================================================
extern "C" void kernel_launch(void* const* d_in, const int* in_sizes, int n_in,
                              void* d_out, int out_size, void* d_ws, size_t ws_size,
                              hipStream_t stream) {
  (void)in_sizes; (void)n_in; (void)out_size; (void)ws_size;
  const float* mem    = (const float*)d_in[0];
  const float* wq     = (const float*)d_in[1];
  const float* bq     = (const float*)d_in[2];
  const float* wk     = (const float*)d_in[3];
  const float* bk     = (const float*)d_in[4];
  const float* wv     = (const float*)d_in[5];
  const float* bv     = (const float*)d_in[6];
  const float* wo     = (const float*)d_in[7];
  const float* bo     = (const float*)d_in[8];
  const float* n1g    = (const float*)d_in[9];
  const float* n1b    = (const float*)d_in[10];
  const float* clng   = (const float*)d_in[11];
  const float* clnb   = (const float*)d_in[12];
  const float* pw1w   = (const float*)d_in[13];
  const float* pw1b   = (const float*)d_in[14];
  const float* dww    = (const float*)d_in[15];
  const float* dwb    = (const float*)d_in[16];
  const float* bng    = (const float*)d_in[17];
  const float* bnb    = (const float*)d_in[18];
  const float* pw2w   = (const float*)d_in[19];
  const float* pw2b   = (const float*)d_in[20];
  const float* projw  = (const float*)d_in[21];
  const float* projb  = (const float*)d_in[22];
  const float* proj2w = (const float*)d_in[23];
  const float* proj2b = (const float*)d_in[24];
  const float* lin1w  = (const float*)d_in[25];
  const float* lin1b  = (const float*)d_in[26];
  const float* lin2w  = (const float*)d_in[27];
  const float* lin2b  = (const float*)d_in[28];
  const float* n3g    = (const float*)d_in[29];
  const float* n3b    = (const float*)d_in[30];
  float* out = (float*)d_out;

  char* base = (char*)d_ws;
  float* qb   = (float*)base;          // q fp32 -> tgt2 fp32
  float* kb   = qb + TD;               // k fp32 -> mem1
  float* big1 = kb + TD;               // h1 lo -> mem2 fp32
  float* big2 = big1 + TD;             // h1 hi -> conv_out
  float* ob   = big2 + TD;             // hg -> ffout
  unsigned short* abf  = (unsigned short*)(base + 5 * TD * 4);  // bf16 hub
  unsigned short* qbf  = abf + TD;     // rope-q -> mem2 bf16
  unsigned short* kbf  = qbf + TD;
  unsigned short* vtb  = kbf + TD;     // V^T bf16  [b][1024 d][2048 l]
  unsigned short* m1T  = vtb + TD;
  unsigned short* ffbbf= m1T + TD;     // NT*FF = 4*TD shorts
  unsigned short* wt   = ffbbf + 4 * TD;
  unsigned short* wqT    = wt;            // [1024][1024] } contiguous => [3072][1024] fused QKV B^T
  unsigned short* wkT    = wqT + MEG;
  unsigned short* wvT    = wkT + MEG;
  unsigned short* woT    = wvT + MEG;
  unsigned short* pw1T   = woT + MEG;     // [2048][1024]
  unsigned short* pw2T   = pw1T + 2*MEG;  // [1024][1024]
  unsigned short* proj2T = pw2T + MEG;    // [1024][1024]
  unsigned short* projwT = proj2T + MEG;  // [2048][2048]
  unsigned short* lin1T  = projwT + 4*MEG;// [4096][1024]
  unsigned short* lin2T  = lin1T + 4*MEG; // [1024][4096]
  float* pet = (float*)(lin2T + 4*MEG);   // [2048][64] rope table

  const dim3 blk(256);
  const long long LD = (long long)Lc * Dc;

  // ---- fused weight transposes + rope table ----
  TPack tp;
  const float* tin[10]  = {wq, wk, wv, wo, pw1w, pw2w, proj2w, projw, lin1w, lin2w};
  unsigned short* tout[10] = {wqT, wkT, wvT, woT, pw1T, pw2T, proj2T, projwT, lin1T, lin2T};
  const int tR[10] = {1024,1024,1024,1024,1024,1024,1024,2048,1024,4096};
  const int tC[10] = {1024,1024,1024,1024,2048,1024,1024,2048,4096,1024};
  int startAcc = 0;
  for (int i = 0; i < 10; i++) {
    tp.in[i] = tin[i]; tp.out[i] = tout[i];
    tp.R[i] = tR[i]; tp.C[i] = tC[i]; tp.tx[i] = tC[i] / 64;
    tp.start[i] = startAcc;
    startAcc += (tR[i] / 64) * (tC[i] / 64);
  }
  fused_transpose_kernel<<<dim3(startAcc), blk, 0, stream>>>(tp);
  pe_fill_kernel<<<dim3(Lc * 64 / 256), blk, 0, stream>>>(pet);

  // ---- attention ----
  convert_bf16_kernel<<<dim3((unsigned)(TD/1024)),blk,0,stream>>>(mem, abf);
  // fused QKV: N=3072, q->qb fp32, k->kb fp32, V->vtb transposed bf16 directly
  mfma_gemm_kernel<128,EPI_QKV,false,false><<<dim3(24,32,1),blk,0,stream>>>(
      abf, wqT, bq, bk, bv, nullptr, qb, vtb, NT, 3*Dc, Dc, 0, 0, 0);
  rope2_kernel<<<dim3(2*NT*Hc/256),blk,0,stream>>>(qb, kb, pet, qbf, kbf);
  flash_attn_mfma_kernel<<<dim3(Lc/64, Bc*Hc),blk,0,stream>>>(qbf,kbf,vtb,abf);
  mfma_gemm_kernel<64,EPI_BIAS,false,false><<<dim3(8,64,1),blk,0,stream>>>(
      abf,woT,bo,nullptr,nullptr,nullptr,qb,nullptr,NT,Dc,Dc,0,0,0);
  // mem1 (fp32 -> kb) and ln(mem1) (bf16 -> abf) in one pass
  ln_res_cln_kernel<<<dim3(NT),blk,0,stream>>>(qb, mem, n1g, n1b, clng, clnb, kb, abf);

  // ---- conv block ----
  mfma_gemm_kernel<128,EPI_BIAS,false,false><<<dim3(16,32,1),blk,0,stream>>>(
      abf,pw1T,pw1b,nullptr,nullptr,nullptr,big1,nullptr,NT,2*Dc,Dc,0,0,0);
  glu_kernel<<<dim3((unsigned)(TD/4/256)),blk,0,stream>>>(big1, ob);
  dwconv_bf16_kernel<<<dim3((unsigned)(TD/256)),blk,0,stream>>>(ob, dww, dwb, bng, bnb, abf);
  mfma_gemm_kernel<64,EPI_ADDROW0,false,false><<<dim3(8,64,1),blk,0,stream>>>(
      abf,pw2T,pw2b,nullptr,nullptr,kb,big2,nullptr,NT,Dc,Dc,0,0,0);

  // ---- proj path ----
  transpose_convert_kernel<<<dim3(16,32,2),blk,0,stream>>>(kb, m1T, 2048, 1024, LD, LD);
  mfma_gemm_kernel<64,EPI_BIAS_ROW,true,false><<<dim3(8,32,2),blk,0,stream>>>(
      projwT,m1T,projb,nullptr,nullptr,nullptr,nullptr,abf,Lc,Dc,Lc,0,LD,LD);
  // mem2 = proj@proj2 + conv_out: fp32 -> big1 AND bf16 -> qbf (feeds lin1)
  mfma_gemm_kernel<64,EPI_ADD,false,true><<<dim3(8,64,1),blk,0,stream>>>(
      abf,proj2T,proj2b,nullptr,nullptr,big2,big1,qbf,NT,Dc,Dc,0,0,0);

  // ---- feed-forward ----
  mfma_gemm_kernel<128,EPI_GELU,true,false><<<dim3(32,32,1),blk,0,stream>>>(
      qbf,lin1T,lin1b,nullptr,nullptr,nullptr,nullptr,ffbbf,NT,FFc,Dc,0,0,0);
  mfma_gemm_kernel<64,EPI_BIAS,false,false><<<dim3(8,64,1),blk,0,stream>>>(
      ffbbf,lin2T,lin2b,nullptr,nullptr,nullptr,ob,nullptr,NT,Dc,FFc,0,0,0);

  // ---- final: out = ln(mem2 + ffout) ----
  ln_sum_kernel<<<dim3(NT),blk,0,stream>>>(big1, ob, n3g, n3b, out);
}